// Round 1
// baseline (1145.111 us; speedup 1.0000x reference)
//
#include <hip/hip_runtime.h>

#define N_NODES 50000
#define N_EDGES 800000
#define EPS_C 1e-5f
#define SLOPE_C 0.01f

// ---------------- GEMM: Y[n][m] = (sum_k A[n][k] * W[k][m]) * nisq[n] ----------------
#define BM 64
#define BN 64
#define BK 16

__global__ __launch_bounds__(256) void gemm_nisq_kernel(
    const float* __restrict__ A, const float* __restrict__ W,
    const float* __restrict__ nisq, float* __restrict__ Y,
    int Nrows, int K, int M) {
  __shared__ float As[BK][BM];
  __shared__ float Bs[BK][BN];
  const int tx = threadIdx.x, ty = threadIdx.y;
  const int tid = ty * 16 + tx;
  const int row0 = blockIdx.x * BM;
  const int col0 = blockIdx.y * BN;
  float acc[4][4] = {};
  // A tile load mapping: thread loads one float4 along K
  const int ar = tid >> 2;          // 0..63 (tile row)
  const int ak = (tid & 3) * 4;     // 0,4,8,12 (k offset)
  // B tile load mapping: thread loads one float4 along M
  const int br = tid >> 4;          // 0..15 (k)
  const int bc = (tid & 15) * 4;    // 0..60 (col offset)
  for (int k0 = 0; k0 < K; k0 += BK) {
    float4 av = make_float4(0.f, 0.f, 0.f, 0.f);
    const int arow = row0 + ar;
    if (arow < Nrows)
      av = *reinterpret_cast<const float4*>(&A[(size_t)arow * K + k0 + ak]);
    As[ak + 0][ar] = av.x;
    As[ak + 1][ar] = av.y;
    As[ak + 2][ar] = av.z;
    As[ak + 3][ar] = av.w;
    const float4 bv =
        *reinterpret_cast<const float4*>(&W[(size_t)(k0 + br) * M + col0 + bc]);
    *reinterpret_cast<float4*>(&Bs[br][bc]) = bv;
    __syncthreads();
#pragma unroll
    for (int kk = 0; kk < BK; ++kk) {
      const float4 a = *reinterpret_cast<const float4*>(&As[kk][ty * 4]);
      const float4 b = *reinterpret_cast<const float4*>(&Bs[kk][tx * 4]);
      const float aa[4] = {a.x, a.y, a.z, a.w};
      const float bb[4] = {b.x, b.y, b.z, b.w};
#pragma unroll
      for (int i = 0; i < 4; ++i)
#pragma unroll
        for (int j = 0; j < 4; ++j) acc[i][j] += aa[i] * bb[j];
    }
    __syncthreads();
  }
#pragma unroll
  for (int i = 0; i < 4; ++i) {
    const int row = row0 + ty * 4 + i;
    if (row < Nrows) {
      const float s = nisq[row];
      float4 o;
      o.x = acc[i][0] * s; o.y = acc[i][1] * s;
      o.z = acc[i][2] * s; o.w = acc[i][3] * s;
      *reinterpret_cast<float4*>(&Y[(size_t)row * M + col0 + tx * 4]) = o;
    }
  }
}

// ---------------- degree histogram ----------------
__global__ void hist_kernel(const int* __restrict__ dst, int* __restrict__ hist, int E) {
  const int e = blockIdx.x * 256 + threadIdx.x;
  if (e < E) atomicAdd(&hist[dst[e]], 1);
}

__global__ void nisq_kernel(const int* __restrict__ hist, float* __restrict__ nisq, int n) {
  const int i = blockIdx.x * 256 + threadIdx.x;
  if (i < n) nisq[i] = rsqrtf((float)hist[i] + 1.0f);
}

// ---------------- exclusive scan (single block, sequential chunks) ----------------
__global__ __launch_bounds__(1024) void scan_kernel(
    const int* __restrict__ hist, int* __restrict__ off, int* __restrict__ cursor, int n) {
  __shared__ int tmp[1024];
  __shared__ int carry;
  const int tid = threadIdx.x;
  if (tid == 0) carry = 0;
  for (int base = 0; base < n; base += 1024) {
    __syncthreads();
    const int cbase = carry;
    const int i = base + tid;
    const int v = (i < n) ? hist[i] : 0;
    tmp[tid] = v;
    __syncthreads();
    int x = v;
    for (int o = 1; o < 1024; o <<= 1) {
      const int y = (tid >= o) ? tmp[tid - o] : 0;
      __syncthreads();
      x += y;
      tmp[tid] = x;
      __syncthreads();
    }
    if (i < n) {
      const int ex = cbase + x - v;
      off[i] = ex;
      cursor[i] = ex;
    }
    if (tid == 1023) carry = cbase + x;
  }
  __syncthreads();
  if (tid == 0) off[n] = carry;
}

// ---------------- scatter edges into dst-sorted order ----------------
__global__ void scatter_kernel(const int* __restrict__ src, const int* __restrict__ dst,
                               int* __restrict__ cursor, int* __restrict__ esorted, int E) {
  const int e = blockIdx.x * 256 + threadIdx.x;
  if (e < E) {
    const int p = atomicAdd(&cursor[dst[e]], 1);
    esorted[p] = src[e];
  }
}

// ---------------- per-node gather aggregation + bias (+residual) ----------------
template <int DO, bool HAS_RES>
__global__ __launch_bounds__(256) void aggregate_kernel(
    const float* __restrict__ Y, const int* __restrict__ segoff,
    const int* __restrict__ esorted, const float* __restrict__ nisq,
    const float* __restrict__ bias, const float* __restrict__ resid,
    float* __restrict__ T) {
  constexpr int V = DO / 64;
  const int wave = threadIdx.x >> 6;
  const int lane = threadIdx.x & 63;
  const int n = blockIdx.x * 4 + wave;
  if (n >= N_NODES) return;
  const int s = segoff[n];
  const int e = segoff[n + 1];
  const int colbase = lane * V;
  float acc[V];
#pragma unroll
  for (int i = 0; i < V; ++i) acc[i] = 0.f;
  for (int j = s; j < e; ++j) {
    const int sid = esorted[j];
    const float* yr = Y + (size_t)sid * DO + colbase;
    if constexpr (V == 4) {
      const float4 v = *reinterpret_cast<const float4*>(yr);
      acc[0] += v.x; acc[1] += v.y; acc[2] += v.z; acc[3] += v.w;
    } else {
      const float2 v = *reinterpret_cast<const float2*>(yr);
      acc[0] += v.x; acc[1] += v.y;
    }
  }
  {  // self-loop term
    const float* yr = Y + (size_t)n * DO + colbase;
    if constexpr (V == 4) {
      const float4 v = *reinterpret_cast<const float4*>(yr);
      acc[0] += v.x; acc[1] += v.y; acc[2] += v.z; acc[3] += v.w;
    } else {
      const float2 v = *reinterpret_cast<const float2*>(yr);
      acc[0] += v.x; acc[1] += v.y;
    }
  }
  const float sc = nisq[n];
#pragma unroll
  for (int i = 0; i < V; ++i) {
    float t = acc[i] * sc + bias[colbase + i];
    if (HAS_RES) t += resid[(size_t)n * DO + colbase + i];
    acc[i] = t;
  }
  float* tr = T + (size_t)n * DO + colbase;
  if constexpr (V == 4) {
    float4 o; o.x = acc[0]; o.y = acc[1]; o.z = acc[2]; o.w = acc[3];
    *reinterpret_cast<float4*>(tr) = o;
  } else {
    float2 o; o.x = acc[0]; o.y = acc[1];
    *reinterpret_cast<float2*>(tr) = o;
  }
}

// ---------------- column sums for BN stats ----------------
__global__ void stats_kernel(const float* __restrict__ T, float* __restrict__ colsum,
                             float* __restrict__ colsumsq, int n, int rowsPerBlock) {
  const int c = threadIdx.x;      // blockDim.x == DO
  const int DO = blockDim.x;
  const int r0 = blockIdx.x * rowsPerBlock;
  int r1 = r0 + rowsPerBlock;
  if (r1 > n) r1 = n;
  float s = 0.f, q = 0.f;
  for (int r = r0; r < r1; ++r) {
    const float v = T[(size_t)r * DO + c];
    s += v;
    q += v * v;
  }
  atomicAdd(&colsum[c], s);
  atomicAdd(&colsumsq[c], q);
}

// ---------------- BN apply + LeakyReLU (in place) ----------------
__global__ void bn_lrelu_kernel(float* __restrict__ T, const float* __restrict__ colsum,
                                const float* __restrict__ colsumsq,
                                const float* __restrict__ g, const float* __restrict__ be,
                                size_t total, unsigned domask, float invN) {
  const size_t idx = (size_t)blockIdx.x * 256 + threadIdx.x;
  if (idx >= total) return;
  const unsigned c = (unsigned)idx & domask;
  const float m = colsum[c] * invN;
  const float v = colsumsq[c] * invN - m * m;
  const float z = (T[idx] - m) * rsqrtf(v + EPS_C) * g[c] + be[c];
  T[idx] = (z >= 0.f) ? z : SLOPE_C * z;
}

// ---------------- final: BN apply + LayerNorm fused (DO=128) ----------------
__global__ __launch_bounds__(256) void bn_ln_kernel(
    const float* __restrict__ T, const float* __restrict__ colsum,
    const float* __restrict__ colsumsq, const float* __restrict__ g,
    const float* __restrict__ be, const float* __restrict__ lng,
    const float* __restrict__ lnb, float* __restrict__ out, float invN) {
  const int wave = threadIdx.x >> 6;
  const int lane = threadIdx.x & 63;
  const int n = blockIdx.x * 4 + wave;
  if (n >= N_NODES) return;
  const int c = lane * 2;
  const float2 t = *reinterpret_cast<const float2*>(&T[(size_t)n * 128 + c]);
  float z[2];
#pragma unroll
  for (int k = 0; k < 2; ++k) {
    const float m = colsum[c + k] * invN;
    const float v = colsumsq[c + k] * invN - m * m;
    const float tv = (k == 0) ? t.x : t.y;
    z[k] = (tv - m) * rsqrtf(v + EPS_C) * g[c + k] + be[c + k];
  }
  float s = z[0] + z[1];
  float q = z[0] * z[0] + z[1] * z[1];
  for (int o = 32; o > 0; o >>= 1) {
    s += __shfl_xor(s, o, 64);
    q += __shfl_xor(q, o, 64);
  }
  const float mean = s * (1.f / 128.f);
  const float var = q * (1.f / 128.f) - mean * mean;
  const float rs = rsqrtf(var + EPS_C);
  float2 o2;
  o2.x = (z[0] - mean) * rs * lng[c] + lnb[c];
  o2.y = (z[1] - mean) * rs * lng[c + 1] + lnb[c + 1];
  *reinterpret_cast<float2*>(&out[(size_t)n * 128 + c]) = o2;
}

extern "C" void kernel_launch(void* const* d_in, const int* in_sizes, int n_in,
                              void* d_out, int out_size, void* d_ws, size_t ws_size,
                              hipStream_t stream) {
  const float* x = (const float*)d_in[0];
  const int* ei = (const int*)d_in[1];
  const int* srcp = ei;
  const int* dstp = ei + N_EDGES;
  const float* W1 = (const float*)d_in[2];
  const float* b1 = (const float*)d_in[3];
  const float* g1 = (const float*)d_in[4];
  const float* be1 = (const float*)d_in[5];
  const float* W2 = (const float*)d_in[6];
  const float* b2 = (const float*)d_in[7];
  const float* g2 = (const float*)d_in[8];
  const float* be2 = (const float*)d_in[9];
  const float* W3 = (const float*)d_in[10];
  const float* b3 = (const float*)d_in[11];
  const float* g3 = (const float*)d_in[12];
  const float* be3 = (const float*)d_in[13];
  const float* W4 = (const float*)d_in[14];
  const float* b4 = (const float*)d_in[15];
  const float* g4 = (const float*)d_in[16];
  const float* be4 = (const float*)d_in[17];
  const float* lng = (const float*)d_in[18];
  const float* lnb = (const float*)d_in[19];
  float* out = (float*)d_out;

  char* ws = (char*)d_ws;
  size_t off_b = 0;
  auto alloc = [&](size_t bytes) -> void* {
    void* p = (void*)(ws + off_b);
    off_b += (bytes + 255) & ~(size_t)255;
    return p;
  };
  int* hist = (int*)alloc((size_t)N_NODES * 4);
  int* segoff = (int*)alloc((size_t)(N_NODES + 1) * 4);
  int* cursor = (int*)alloc((size_t)N_NODES * 4);
  float* nisq = (float*)alloc((size_t)N_NODES * 4);
  int* esorted = (int*)alloc((size_t)N_EDGES * 4);
  float* colsum = (float*)alloc(256 * 4);
  float* colsumsq = (float*)alloc(256 * 4);
  float* bufA = (float*)alloc((size_t)N_NODES * 256 * 4);
  float* bufB = (float*)alloc((size_t)N_NODES * 256 * 4);
  float* bufC = (float*)alloc((size_t)N_NODES * 256 * 4);

  const float invN = 1.0f / (float)N_NODES;
  const int egrid = (N_EDGES + 255) / 256;
  const int ngrid = (N_NODES + 255) / 256;
  const int aggrid = (N_NODES + 3) / 4;
  const int statgrid = (N_NODES + 127) / 128;
  const dim3 gblock(16, 16);
  const dim3 ggrid256((N_NODES + BM - 1) / BM, 256 / BN);
  const dim3 ggrid128((N_NODES + BM - 1) / BM, 128 / BN);

  // ---- degrees + dst-sorted edge list (counting sort) ----
  hipMemsetAsync(hist, 0, (size_t)N_NODES * 4, stream);
  hist_kernel<<<egrid, 256, 0, stream>>>(dstp, hist, N_EDGES);
  nisq_kernel<<<ngrid, 256, 0, stream>>>(hist, nisq, N_NODES);
  scan_kernel<<<1, 1024, 0, stream>>>(hist, segoff, cursor, N_NODES);
  scatter_kernel<<<egrid, 256, 0, stream>>>(srcp, dstp, cursor, esorted, N_EDGES);

  // ---- Layer 1: x(128) -> 256 ----
  gemm_nisq_kernel<<<ggrid256, gblock, 0, stream>>>(x, W1, nisq, bufA, N_NODES, 128, 256);
  aggregate_kernel<256, false><<<aggrid, 256, 0, stream>>>(bufA, segoff, esorted, nisq, b1, nullptr, bufB);
  hipMemsetAsync(colsum, 0, 2048, stream);
  stats_kernel<<<statgrid, 256, 0, stream>>>(bufB, colsum, colsumsq, N_NODES, 128);
  bn_lrelu_kernel<<<(unsigned)(((size_t)N_NODES * 256 + 255) / 256), 256, 0, stream>>>(
      bufB, colsum, colsumsq, g1, be1, (size_t)N_NODES * 256, 255u, invN);

  // ---- Layer 2: 256 -> 256 ----
  gemm_nisq_kernel<<<ggrid256, gblock, 0, stream>>>(bufB, W2, nisq, bufA, N_NODES, 256, 256);
  aggregate_kernel<256, false><<<aggrid, 256, 0, stream>>>(bufA, segoff, esorted, nisq, b2, nullptr, bufC);
  hipMemsetAsync(colsum, 0, 2048, stream);
  stats_kernel<<<statgrid, 256, 0, stream>>>(bufC, colsum, colsumsq, N_NODES, 128);
  bn_lrelu_kernel<<<(unsigned)(((size_t)N_NODES * 256 + 255) / 256), 256, 0, stream>>>(
      bufC, colsum, colsumsq, g2, be2, (size_t)N_NODES * 256, 255u, invN);

  // ---- Layer 3: 256 -> 256 ----
  gemm_nisq_kernel<<<ggrid256, gblock, 0, stream>>>(bufC, W3, nisq, bufA, N_NODES, 256, 256);
  aggregate_kernel<256, false><<<aggrid, 256, 0, stream>>>(bufA, segoff, esorted, nisq, b3, nullptr, bufB);
  hipMemsetAsync(colsum, 0, 2048, stream);
  stats_kernel<<<statgrid, 256, 0, stream>>>(bufB, colsum, colsumsq, N_NODES, 128);
  bn_lrelu_kernel<<<(unsigned)(((size_t)N_NODES * 256 + 255) / 256), 256, 0, stream>>>(
      bufB, colsum, colsumsq, g3, be3, (size_t)N_NODES * 256, 255u, invN);

  // ---- Layer 4: 256 -> 128, residual + BN + LayerNorm ----
  gemm_nisq_kernel<<<ggrid128, gblock, 0, stream>>>(bufB, W4, nisq, bufA, N_NODES, 256, 128);
  aggregate_kernel<128, true><<<aggrid, 256, 0, stream>>>(bufA, segoff, esorted, nisq, b4, x, bufC);
  hipMemsetAsync(colsum, 0, 2048, stream);
  stats_kernel<<<statgrid, 128, 0, stream>>>(bufC, colsum, colsumsq, N_NODES, 128);
  bn_ln_kernel<<<aggrid, 256, 0, stream>>>(bufC, colsum, colsumsq, g4, be4, lng, lnb, out, invN);
}

// Round 2
// 861.437 us; speedup vs baseline: 1.3293x; 1.3293x over previous
//
#include <hip/hip_runtime.h>

#define N_NODES 50000
#define N_EDGES 800000
#define EPS_C 1e-5f
#define SLOPE_C 0.01f

// ---------- bf16 helpers (RNE) ----------
__device__ __forceinline__ unsigned short f2bf(float f) {
  unsigned u = __float_as_uint(f);
  u += 0x7fffu + ((u >> 16) & 1u);
  return (unsigned short)(u >> 16);
}
__device__ __forceinline__ float bflo(unsigned u) { return __uint_as_float(u << 16); }
__device__ __forceinline__ float bfhi(unsigned u) { return __uint_as_float(u & 0xffff0000u); }

// ---------------- GEMM: acc = A·W; epilogue either (acc*nisq[row])->bf16 or (acc+bias)->f32 ----
#define BM 64
#define BN 64
#define BK 16

template <bool NISQ_EPI, bool BF16OUT>
__global__ __launch_bounds__(256) void gemm_kernel(
    const float* __restrict__ A, const float* __restrict__ W,
    const float* __restrict__ aux, void* __restrict__ Yv,
    int Nrows, int K, int M) {
  __shared__ float As[BK][BM];
  __shared__ float Bs[BK][BN];
  const int tx = threadIdx.x, ty = threadIdx.y;
  const int tid = ty * 16 + tx;
  const int row0 = blockIdx.x * BM;
  const int col0 = blockIdx.y * BN;
  float acc[4][4] = {};
  const int ar = tid >> 2;
  const int ak = (tid & 3) * 4;
  const int br = tid >> 4;
  const int bc = (tid & 15) * 4;
  for (int k0 = 0; k0 < K; k0 += BK) {
    float4 av = make_float4(0.f, 0.f, 0.f, 0.f);
    const int arow = row0 + ar;
    if (arow < Nrows)
      av = *reinterpret_cast<const float4*>(&A[(size_t)arow * K + k0 + ak]);
    As[ak + 0][ar] = av.x;
    As[ak + 1][ar] = av.y;
    As[ak + 2][ar] = av.z;
    As[ak + 3][ar] = av.w;
    const float4 bv =
        *reinterpret_cast<const float4*>(&W[(size_t)(k0 + br) * M + col0 + bc]);
    *reinterpret_cast<float4*>(&Bs[br][bc]) = bv;
    __syncthreads();
#pragma unroll
    for (int kk = 0; kk < BK; ++kk) {
      const float4 a = *reinterpret_cast<const float4*>(&As[kk][ty * 4]);
      const float4 b = *reinterpret_cast<const float4*>(&Bs[kk][tx * 4]);
      const float aa[4] = {a.x, a.y, a.z, a.w};
      const float bb[4] = {b.x, b.y, b.z, b.w};
#pragma unroll
      for (int i = 0; i < 4; ++i)
#pragma unroll
        for (int j = 0; j < 4; ++j) acc[i][j] += aa[i] * bb[j];
    }
    __syncthreads();
  }
#pragma unroll
  for (int i = 0; i < 4; ++i) {
    const int row = row0 + ty * 4 + i;
    if (row < Nrows) {
      float4 o;
      if constexpr (NISQ_EPI) {
        const float s = aux[row];
        o.x = acc[i][0] * s; o.y = acc[i][1] * s;
        o.z = acc[i][2] * s; o.w = acc[i][3] * s;
      } else {
        const float4 bv = *reinterpret_cast<const float4*>(&aux[col0 + tx * 4]);
        o.x = acc[i][0] + bv.x; o.y = acc[i][1] + bv.y;
        o.z = acc[i][2] + bv.z; o.w = acc[i][3] + bv.w;
      }
      if constexpr (BF16OUT) {
        ushort4 ob;
        ob.x = f2bf(o.x); ob.y = f2bf(o.y); ob.z = f2bf(o.z); ob.w = f2bf(o.w);
        *reinterpret_cast<ushort4*>(
            (unsigned short*)Yv + (size_t)row * M + col0 + tx * 4) = ob;
      } else {
        *reinterpret_cast<float4*>((float*)Yv + (size_t)row * M + col0 + tx * 4) = o;
      }
    }
  }
}

// ---------------- degree histogram ----------------
__global__ void hist_kernel(const int* __restrict__ dst, int* __restrict__ hist, int E) {
  const int e = blockIdx.x * 256 + threadIdx.x;
  if (e < E) atomicAdd(&hist[dst[e]], 1);
}

__global__ void nisq_kernel(const int* __restrict__ hist, float* __restrict__ nisq, int n) {
  const int i = blockIdx.x * 256 + threadIdx.x;
  if (i < n) nisq[i] = rsqrtf((float)hist[i] + 1.0f);
}

// ---------------- two-level exclusive scan ----------------
__global__ __launch_bounds__(1024) void scan1_kernel(
    const int* __restrict__ hist, int* __restrict__ off, int* __restrict__ partial, int n) {
  __shared__ int tmp[1024];
  const int tid = threadIdx.x;
  const int i = blockIdx.x * 1024 + tid;
  const int v = (i < n) ? hist[i] : 0;
  tmp[tid] = v;
  __syncthreads();
  int x = v;
  for (int o = 1; o < 1024; o <<= 1) {
    const int y = (tid >= o) ? tmp[tid - o] : 0;
    __syncthreads();
    x += y;
    tmp[tid] = x;
    __syncthreads();
  }
  if (i < n) off[i] = x - v;  // block-local exclusive
  if (tid == 1023) partial[blockIdx.x] = x;
}

__global__ __launch_bounds__(64) void scan2_kernel(
    const int* __restrict__ partial, int* __restrict__ partialoff,
    int* __restrict__ offN, int nb) {
  const int tid = threadIdx.x;
  const int v = (tid < nb) ? partial[tid] : 0;
  int x = v;
  for (int o = 1; o < 64; o <<= 1) {
    const int y = __shfl_up(x, o, 64);
    if (tid >= o) x += y;
  }
  if (tid < nb) partialoff[tid] = x - v;
  if (tid == 63) *offN = x;  // grand total
}

__global__ void scan3_kernel(int* __restrict__ off, int* __restrict__ cursor,
                             const int* __restrict__ partialoff, int n) {
  const int i = blockIdx.x * 256 + threadIdx.x;
  if (i < n) {
    const int o = off[i] + partialoff[i >> 10];
    off[i] = o;
    cursor[i] = o;
  }
}

// ---------------- scatter edges into dst-sorted order ----------------
__global__ void scatter_kernel(const int* __restrict__ src, const int* __restrict__ dst,
                               int* __restrict__ cursor, int* __restrict__ esorted, int E) {
  const int e = blockIdx.x * 256 + threadIdx.x;
  if (e < E) {
    const int p = atomicAdd(&cursor[dst[e]], 1);
    esorted[p] = src[e];
  }
}

// ---------------- scale+cast: xs = bf16(x * nisq[row]), DI=128 ----------------
__global__ void scale_cast_kernel(const float* __restrict__ x,
                                  const float* __restrict__ nisq,
                                  unsigned short* __restrict__ xs) {
  const int idx = blockIdx.x * 256 + threadIdx.x;  // each handles 4 elems
  if (idx >= N_NODES * 32) return;
  const int row = idx >> 5;
  const int c = (idx & 31) * 4;
  const float s = nisq[row];
  const float4 v = *reinterpret_cast<const float4*>(&x[(size_t)row * 128 + c]);
  ushort4 o;
  o.x = f2bf(v.x * s); o.y = f2bf(v.y * s);
  o.z = f2bf(v.z * s); o.w = f2bf(v.w * s);
  *reinterpret_cast<ushort4*>(&xs[(size_t)row * 128 + c]) = o;
}

// ---------------- per-node gather aggregation over bf16 rows ----------------
template <int DO, bool ADD_BIAS, bool HAS_RES>
__global__ __launch_bounds__(256) void aggregate_bf16_kernel(
    const unsigned short* __restrict__ Y, const int* __restrict__ segoff,
    const int* __restrict__ esorted, const float* __restrict__ nisq,
    const float* __restrict__ bias, const float* __restrict__ resid,
    float* __restrict__ T) {
  constexpr int V = DO / 64;
  const int wave = threadIdx.x >> 6;
  const int lane = threadIdx.x & 63;
  const int n = blockIdx.x * 4 + wave;
  if (n >= N_NODES) return;
  const int s = segoff[n];
  const int e = segoff[n + 1];
  const int colbase = lane * V;
  float acc[V], acc2[V];
#pragma unroll
  for (int i = 0; i < V; ++i) { acc[i] = 0.f; acc2[i] = 0.f; }

  auto addrow = [&](float* a, int rid) {
    const unsigned short* yr = Y + (size_t)rid * DO + colbase;
    if constexpr (V == 4) {
      const uint2 v = *reinterpret_cast<const uint2*>(yr);
      a[0] += bflo(v.x); a[1] += bfhi(v.x);
      a[2] += bflo(v.y); a[3] += bfhi(v.y);
    } else {
      const unsigned v = *reinterpret_cast<const unsigned*>(yr);
      a[0] += bflo(v); a[1] += bfhi(v);
    }
  };

  int j = s;
  for (; j + 1 < e; j += 2) {
    const int s0 = esorted[j];
    const int s1 = esorted[j + 1];
    addrow(acc, s0);
    addrow(acc2, s1);
  }
  if (j < e) addrow(acc, esorted[j]);
  addrow(acc2, n);  // self loop

  const float sc = nisq[n];
#pragma unroll
  for (int i = 0; i < V; ++i) {
    float t = (acc[i] + acc2[i]) * sc;
    if (ADD_BIAS) t += bias[colbase + i];
    if (HAS_RES) t += resid[(size_t)n * DO + colbase + i];
    acc[i] = t;
  }
  float* tr = T + (size_t)n * DO + colbase;
  if constexpr (V == 4) {
    float4 o; o.x = acc[0]; o.y = acc[1]; o.z = acc[2]; o.w = acc[3];
    *reinterpret_cast<float4*>(tr) = o;
  } else {
    float2 o; o.x = acc[0]; o.y = acc[1];
    *reinterpret_cast<float2*>(tr) = o;
  }
}

// ---------------- column sums for BN stats ----------------
__global__ void stats_kernel(const float* __restrict__ T, float* __restrict__ colsum,
                             float* __restrict__ colsumsq, int n, int rowsPerBlock) {
  const int c = threadIdx.x;  // blockDim.x == DO
  const int DO = blockDim.x;
  const int r0 = blockIdx.x * rowsPerBlock;
  int r1 = r0 + rowsPerBlock;
  if (r1 > n) r1 = n;
  float s = 0.f, q = 0.f;
  for (int r = r0; r < r1; ++r) {
    const float v = T[(size_t)r * DO + c];
    s += v;
    q += v * v;
  }
  atomicAdd(&colsum[c], s);
  atomicAdd(&colsumsq[c], q);
}

// ---------------- BN apply + LeakyReLU (in place, float4) ----------------
__global__ void bn_lrelu_kernel(float* __restrict__ T, const float* __restrict__ colsum,
                                const float* __restrict__ colsumsq,
                                const float* __restrict__ g, const float* __restrict__ be,
                                size_t total4, unsigned domask4, float invN) {
  const size_t idx = (size_t)blockIdx.x * 256 + threadIdx.x;
  if (idx >= total4) return;
  const unsigned c = ((unsigned)idx & domask4) * 4;
  const float4 cs = *reinterpret_cast<const float4*>(&colsum[c]);
  const float4 cq = *reinterpret_cast<const float4*>(&colsumsq[c]);
  const float4 gv = *reinterpret_cast<const float4*>(&g[c]);
  const float4 bv = *reinterpret_cast<const float4*>(&be[c]);
  float4 t = *reinterpret_cast<float4*>(&T[idx * 4]);
  const float m0 = cs.x * invN, m1 = cs.y * invN, m2 = cs.z * invN, m3 = cs.w * invN;
  const float r0 = rsqrtf(cq.x * invN - m0 * m0 + EPS_C);
  const float r1 = rsqrtf(cq.y * invN - m1 * m1 + EPS_C);
  const float r2 = rsqrtf(cq.z * invN - m2 * m2 + EPS_C);
  const float r3 = rsqrtf(cq.w * invN - m3 * m3 + EPS_C);
  float z;
  z = (t.x - m0) * r0 * gv.x + bv.x; t.x = (z >= 0.f) ? z : SLOPE_C * z;
  z = (t.y - m1) * r1 * gv.y + bv.y; t.y = (z >= 0.f) ? z : SLOPE_C * z;
  z = (t.z - m2) * r2 * gv.z + bv.z; t.z = (z >= 0.f) ? z : SLOPE_C * z;
  z = (t.w - m3) * r3 * gv.w + bv.w; t.w = (z >= 0.f) ? z : SLOPE_C * z;
  *reinterpret_cast<float4*>(&T[idx * 4]) = t;
}

// ---------------- final: BN apply + LayerNorm fused (DO=128) ----------------
__global__ __launch_bounds__(256) void bn_ln_kernel(
    const float* __restrict__ T, const float* __restrict__ colsum,
    const float* __restrict__ colsumsq, const float* __restrict__ g,
    const float* __restrict__ be, const float* __restrict__ lng,
    const float* __restrict__ lnb, float* __restrict__ out, float invN) {
  const int wave = threadIdx.x >> 6;
  const int lane = threadIdx.x & 63;
  const int n = blockIdx.x * 4 + wave;
  if (n >= N_NODES) return;
  const int c = lane * 2;
  const float2 t = *reinterpret_cast<const float2*>(&T[(size_t)n * 128 + c]);
  float z[2];
#pragma unroll
  for (int k = 0; k < 2; ++k) {
    const float m = colsum[c + k] * invN;
    const float v = colsumsq[c + k] * invN - m * m;
    const float tv = (k == 0) ? t.x : t.y;
    z[k] = (tv - m) * rsqrtf(v + EPS_C) * g[c + k] + be[c + k];
  }
  float s = z[0] + z[1];
  float q = z[0] * z[0] + z[1] * z[1];
  for (int o = 32; o > 0; o >>= 1) {
    s += __shfl_xor(s, o, 64);
    q += __shfl_xor(q, o, 64);
  }
  const float mean = s * (1.f / 128.f);
  const float var = q * (1.f / 128.f) - mean * mean;
  const float rs = rsqrtf(var + EPS_C);
  float2 o2;
  o2.x = (z[0] - mean) * rs * lng[c] + lnb[c];
  o2.y = (z[1] - mean) * rs * lng[c + 1] + lnb[c + 1];
  *reinterpret_cast<float2*>(&out[(size_t)n * 128 + c]) = o2;
}

extern "C" void kernel_launch(void* const* d_in, const int* in_sizes, int n_in,
                              void* d_out, int out_size, void* d_ws, size_t ws_size,
                              hipStream_t stream) {
  const float* x = (const float*)d_in[0];
  const int* ei = (const int*)d_in[1];
  const int* srcp = ei;
  const int* dstp = ei + N_EDGES;
  const float* W1 = (const float*)d_in[2];
  const float* b1 = (const float*)d_in[3];
  const float* g1 = (const float*)d_in[4];
  const float* be1 = (const float*)d_in[5];
  const float* W2 = (const float*)d_in[6];
  const float* b2 = (const float*)d_in[7];
  const float* g2 = (const float*)d_in[8];
  const float* be2 = (const float*)d_in[9];
  const float* W3 = (const float*)d_in[10];
  const float* b3 = (const float*)d_in[11];
  const float* g3 = (const float*)d_in[12];
  const float* be3 = (const float*)d_in[13];
  const float* W4 = (const float*)d_in[14];
  const float* b4 = (const float*)d_in[15];
  const float* g4 = (const float*)d_in[16];
  const float* be4 = (const float*)d_in[17];
  const float* lng = (const float*)d_in[18];
  const float* lnb = (const float*)d_in[19];
  float* out = (float*)d_out;

  char* ws = (char*)d_ws;
  size_t off_b = 0;
  auto alloc = [&](size_t bytes) -> void* {
    void* p = (void*)(ws + off_b);
    off_b += (bytes + 255) & ~(size_t)255;
    return p;
  };
  int* hist = (int*)alloc((size_t)N_NODES * 4);
  int* segoff = (int*)alloc((size_t)(N_NODES + 1) * 4);
  int* cursor = (int*)alloc((size_t)N_NODES * 4);
  float* nisq = (float*)alloc((size_t)N_NODES * 4);
  int* esorted = (int*)alloc((size_t)N_EDGES * 4);
  int* partial = (int*)alloc(64 * 4);
  int* partialoff = (int*)alloc(64 * 4);
  float* colsum = (float*)alloc(256 * 4);
  float* colsumsq = (float*)alloc(256 * 4);
  float* bufB = (float*)alloc((size_t)N_NODES * 256 * 4);
  float* bufC = (float*)alloc((size_t)N_NODES * 256 * 4);
  unsigned short* Ybf = (unsigned short*)alloc((size_t)N_NODES * 256 * 2);
  // aliases (lifetimes verified disjoint):
  unsigned short* xsb = (unsigned short*)bufB;  // N x 128 bf16, dead before gemm L1 writes bufB
  float* xa = bufC;                             // N x 128 f32, dead before aggregate L2 writes bufC

  const float invN = 1.0f / (float)N_NODES;
  const int egrid = (N_EDGES + 255) / 256;
  const int ngrid = (N_NODES + 255) / 256;
  const int aggrid = (N_NODES + 3) / 4;
  const int statgrid = (N_NODES + 127) / 128;
  const int nb = (N_NODES + 1023) / 1024;  // 49 scan blocks
  const dim3 gblock(16, 16);
  const dim3 ggrid256((N_NODES + BM - 1) / BM, 256 / BN);
  const dim3 ggrid128((N_NODES + BM - 1) / BM, 128 / BN);
  const unsigned bngrid256 = (unsigned)(((size_t)N_NODES * 64 + 255) / 256);

  // ---- degrees + dst-sorted edge list (counting sort) ----
  hipMemsetAsync(hist, 0, (size_t)N_NODES * 4, stream);
  hist_kernel<<<egrid, 256, 0, stream>>>(dstp, hist, N_EDGES);
  nisq_kernel<<<ngrid, 256, 0, stream>>>(hist, nisq, N_NODES);
  scan1_kernel<<<nb, 1024, 0, stream>>>(hist, segoff, partial, N_NODES);
  scan2_kernel<<<1, 64, 0, stream>>>(partial, partialoff, &segoff[N_NODES], nb);
  scan3_kernel<<<ngrid, 256, 0, stream>>>(segoff, cursor, partialoff, N_NODES);
  scatter_kernel<<<egrid, 256, 0, stream>>>(srcp, dstp, cursor, esorted, N_EDGES);

  // ---- Layer 1: aggregate input first (A_hat x), then GEMM 128->256 + bias ----
  scale_cast_kernel<<<(N_NODES * 32 + 255) / 256, 256, 0, stream>>>(x, nisq, xsb);
  aggregate_bf16_kernel<128, false, false><<<aggrid, 256, 0, stream>>>(
      xsb, segoff, esorted, nisq, nullptr, nullptr, xa);
  gemm_kernel<false, false><<<ggrid256, gblock, 0, stream>>>(xa, W1, b1, bufB, N_NODES, 128, 256);
  hipMemsetAsync(colsum, 0, 2048, stream);
  stats_kernel<<<statgrid, 256, 0, stream>>>(bufB, colsum, colsumsq, N_NODES, 128);
  bn_lrelu_kernel<<<bngrid256, 256, 0, stream>>>(bufB, colsum, colsumsq, g1, be1,
                                                 (size_t)N_NODES * 64, 63u, invN);

  // ---- Layer 2: 256 -> 256 ----
  gemm_kernel<true, true><<<ggrid256, gblock, 0, stream>>>(bufB, W2, nisq, Ybf, N_NODES, 256, 256);
  aggregate_bf16_kernel<256, true, false><<<aggrid, 256, 0, stream>>>(
      Ybf, segoff, esorted, nisq, b2, nullptr, bufC);
  hipMemsetAsync(colsum, 0, 2048, stream);
  stats_kernel<<<statgrid, 256, 0, stream>>>(bufC, colsum, colsumsq, N_NODES, 128);
  bn_lrelu_kernel<<<bngrid256, 256, 0, stream>>>(bufC, colsum, colsumsq, g2, be2,
                                                 (size_t)N_NODES * 64, 63u, invN);

  // ---- Layer 3: 256 -> 256 ----
  gemm_kernel<true, true><<<ggrid256, gblock, 0, stream>>>(bufC, W3, nisq, Ybf, N_NODES, 256, 256);
  aggregate_bf16_kernel<256, true, false><<<aggrid, 256, 0, stream>>>(
      Ybf, segoff, esorted, nisq, b3, nullptr, bufB);
  hipMemsetAsync(colsum, 0, 2048, stream);
  stats_kernel<<<statgrid, 256, 0, stream>>>(bufB, colsum, colsumsq, N_NODES, 128);
  bn_lrelu_kernel<<<bngrid256, 256, 0, stream>>>(bufB, colsum, colsumsq, g3, be3,
                                                 (size_t)N_NODES * 64, 63u, invN);

  // ---- Layer 4: 256 -> 128, residual + BN + LayerNorm ----
  gemm_kernel<true, true><<<ggrid128, gblock, 0, stream>>>(bufB, W4, nisq, Ybf, N_NODES, 256, 128);
  aggregate_bf16_kernel<128, true, true><<<aggrid, 256, 0, stream>>>(
      Ybf, segoff, esorted, nisq, b4, x, bufC);
  hipMemsetAsync(colsum, 0, 2048, stream);
  stats_kernel<<<statgrid, 128, 0, stream>>>(bufC, colsum, colsumsq, N_NODES, 128);
  bn_ln_kernel<<<aggrid, 256, 0, stream>>>(bufC, colsum, colsumsq, g4, be4, lng, lnb, out, invN);
}

// Round 3
// 671.937 us; speedup vs baseline: 1.7042x; 1.2820x over previous
//
#include <hip/hip_runtime.h>

#define N_NODES 50000
#define N_EDGES 800000
#define EPS_C 1e-5f
#define SLOPE_C 0.01f

typedef __attribute__((ext_vector_type(8))) short short8v;
typedef __attribute__((ext_vector_type(4))) float f32x4;

// ---------- bf16 helpers (RNE) ----------
__device__ __forceinline__ unsigned short f2bf(float f) {
  unsigned u = __float_as_uint(f);
  u += 0x7fffu + ((u >> 16) & 1u);
  return (unsigned short)(u >> 16);
}
__device__ __forceinline__ float bflo(unsigned u) { return __uint_as_float(u << 16); }
__device__ __forceinline__ float bfhi(unsigned u) { return __uint_as_float(u & 0xffff0000u); }

// ---------------- W transpose + cast: Wt[m][k] = bf16(W[k][m]) ----------------
__global__ void wcast_kernel(const float* __restrict__ W, unsigned short* __restrict__ Wt,
                             int total, int mshift, int mmask, int K) {
  const int idx = blockIdx.x * 256 + threadIdx.x;
  if (idx >= total) return;
  const int k = idx >> mshift;
  const int m = idx & mmask;
  Wt[(size_t)m * K + k] = f2bf(W[idx]);
}

// ---------------- MFMA GEMM: acc = A(bf16) · Wt(bf16)^T epilogues as before ----------------
// A: Nrows x K bf16 row-major. Wt: M x K bf16 row-major (so B[k][m] = Wt[m][k]).
// Block tile 128(M-rows) x 64(N-cols), BK=64, 4 waves as 2x2.
template <bool NISQ_EPI, bool BF16OUT>
__global__ __launch_bounds__(256) void gemm_mfma_kernel(
    const unsigned short* __restrict__ A, const unsigned short* __restrict__ Wt,
    const float* __restrict__ aux, void* __restrict__ Yv,
    int Nrows, int K, int M) {
  __shared__ __align__(16) unsigned short As[128][72];
  __shared__ __align__(16) unsigned short Bs[64][72];
  const int tid = threadIdx.x;
  const int lane = tid & 63;
  const int wave = tid >> 6;
  const int wr = wave >> 1, wc = wave & 1;
  const int row0 = blockIdx.x * 128;
  const int col0 = blockIdx.y * 64;
  const int l15 = lane & 15;
  const int lhi = lane >> 4;
  f32x4 acc[4][2];
#pragma unroll
  for (int i = 0; i < 4; ++i)
#pragma unroll
    for (int j = 0; j < 2; ++j) acc[i][j] = (f32x4){0.f, 0.f, 0.f, 0.f};

  for (int k0 = 0; k0 < K; k0 += 64) {
    // stage A tile: 128 rows x 64 k (each thread 4x 16B chunks)
#pragma unroll
    for (int c = 0; c < 4; ++c) {
      const int id = tid + c * 256;
      const int r = id >> 3;
      const int ck = (id & 7) * 8;
      short8v v = {};
      const int grow = row0 + r;
      if (grow < Nrows)
        v = *reinterpret_cast<const short8v*>(&A[(size_t)grow * K + k0 + ck]);
      *reinterpret_cast<short8v*>(&As[r][ck]) = v;
    }
    // stage B tile: 64 cols x 64 k (each thread 2x 16B chunks)
#pragma unroll
    for (int c = 0; c < 2; ++c) {
      const int id = tid + c * 256;
      const int r = id >> 3;
      const int ck = (id & 7) * 8;
      const short8v v =
          *reinterpret_cast<const short8v*>(&Wt[(size_t)(col0 + r) * K + k0 + ck]);
      *reinterpret_cast<short8v*>(&Bs[r][ck]) = v;
    }
    __syncthreads();
    short8v bfr[2][2];
#pragma unroll
    for (int nr = 0; nr < 2; ++nr)
#pragma unroll
      for (int h = 0; h < 2; ++h)
        bfr[nr][h] = *reinterpret_cast<const short8v*>(
            &Bs[wc * 32 + nr * 16 + l15][h * 32 + lhi * 8]);
#pragma unroll
    for (int mr = 0; mr < 4; ++mr) {
#pragma unroll
      for (int h = 0; h < 2; ++h) {
        const short8v af = *reinterpret_cast<const short8v*>(
            &As[wr * 64 + mr * 16 + l15][h * 32 + lhi * 8]);
#pragma unroll
        for (int nr = 0; nr < 2; ++nr)
          acc[mr][nr] = __builtin_amdgcn_mfma_f32_16x16x32_bf16(
              af, bfr[nr][h], acc[mr][nr], 0, 0, 0);
      }
    }
    __syncthreads();
  }
  // epilogue: D[i][j] -> lane = j + 16*(i/4), reg = i%4
#pragma unroll
  for (int mr = 0; mr < 4; ++mr) {
#pragma unroll
    for (int r = 0; r < 4; ++r) {
      const int grow = row0 + wr * 64 + mr * 16 + lhi * 4 + r;
      if (grow < Nrows) {
        if constexpr (NISQ_EPI) {
          const float s = aux[grow];
          unsigned short* Y = (unsigned short*)Yv;
#pragma unroll
          for (int nr = 0; nr < 2; ++nr) {
            const int gcol = col0 + wc * 32 + nr * 16 + l15;
            Y[(size_t)grow * M + gcol] = f2bf(acc[mr][nr][r] * s);
          }
        } else {
          float* Y = (float*)Yv;
#pragma unroll
          for (int nr = 0; nr < 2; ++nr) {
            const int gcol = col0 + wc * 32 + nr * 16 + l15;
            Y[(size_t)grow * M + gcol] = acc[mr][nr][r] + aux[gcol];
          }
        }
      }
    }
  }
}

// ---------------- degree histogram ----------------
__global__ void hist_kernel(const int* __restrict__ dst, int* __restrict__ hist, int E) {
  const int e = blockIdx.x * 256 + threadIdx.x;
  if (e < E) atomicAdd(&hist[dst[e]], 1);
}

__global__ void nisq_kernel(const int* __restrict__ hist, float* __restrict__ nisq, int n) {
  const int i = blockIdx.x * 256 + threadIdx.x;
  if (i < n) nisq[i] = rsqrtf((float)hist[i] + 1.0f);
}

// ---------------- two-level exclusive scan ----------------
__global__ __launch_bounds__(1024) void scan1_kernel(
    const int* __restrict__ hist, int* __restrict__ off, int* __restrict__ partial, int n) {
  __shared__ int tmp[1024];
  const int tid = threadIdx.x;
  const int i = blockIdx.x * 1024 + tid;
  const int v = (i < n) ? hist[i] : 0;
  tmp[tid] = v;
  __syncthreads();
  int x = v;
  for (int o = 1; o < 1024; o <<= 1) {
    const int y = (tid >= o) ? tmp[tid - o] : 0;
    __syncthreads();
    x += y;
    tmp[tid] = x;
    __syncthreads();
  }
  if (i < n) off[i] = x - v;
  if (tid == 1023) partial[blockIdx.x] = x;
}

__global__ __launch_bounds__(64) void scan2_kernel(
    const int* __restrict__ partial, int* __restrict__ partialoff,
    int* __restrict__ offN, int nb) {
  const int tid = threadIdx.x;
  const int v = (tid < nb) ? partial[tid] : 0;
  int x = v;
  for (int o = 1; o < 64; o <<= 1) {
    const int y = __shfl_up(x, o, 64);
    if (tid >= o) x += y;
  }
  if (tid < nb) partialoff[tid] = x - v;
  if (tid == 63) *offN = x;
}

__global__ void scan3_kernel(int* __restrict__ off, int* __restrict__ cursor,
                             const int* __restrict__ partialoff, int n) {
  const int i = blockIdx.x * 256 + threadIdx.x;
  if (i < n) {
    const int o = off[i] + partialoff[i >> 10];
    off[i] = o;
    cursor[i] = o;
  }
}

// ---------------- scatter edges into dst-sorted order ----------------
__global__ void scatter_kernel(const int* __restrict__ src, const int* __restrict__ dst,
                               int* __restrict__ cursor, int* __restrict__ esorted, int E) {
  const int e = blockIdx.x * 256 + threadIdx.x;
  if (e < E) {
    const int p = atomicAdd(&cursor[dst[e]], 1);
    esorted[p] = src[e];
  }
}

// ---------------- scale+cast: xs = bf16(x * nisq[row]), DI=128 ----------------
__global__ void scale_cast_kernel(const float* __restrict__ x,
                                  const float* __restrict__ nisq,
                                  unsigned short* __restrict__ xs) {
  const int idx = blockIdx.x * 256 + threadIdx.x;
  if (idx >= N_NODES * 32) return;
  const int row = idx >> 5;
  const int c = (idx & 31) * 4;
  const float s = nisq[row];
  const float4 v = *reinterpret_cast<const float4*>(&x[(size_t)row * 128 + c]);
  ushort4 o;
  o.x = f2bf(v.x * s); o.y = f2bf(v.y * s);
  o.z = f2bf(v.z * s); o.w = f2bf(v.w * s);
  *reinterpret_cast<ushort4*>(&xs[(size_t)row * 128 + c]) = o;
}

// ---------------- per-node gather aggregation over bf16 rows ----------------
template <int DO, bool ADD_BIAS, bool HAS_RES, bool OUT_BF16>
__global__ __launch_bounds__(256) void aggregate_bf16_kernel(
    const unsigned short* __restrict__ Y, const int* __restrict__ segoff,
    const int* __restrict__ esorted, const float* __restrict__ nisq,
    const float* __restrict__ bias, const float* __restrict__ resid,
    void* __restrict__ Tv) {
  constexpr int V = DO / 64;
  const int wave = threadIdx.x >> 6;
  const int lane = threadIdx.x & 63;
  const int n = blockIdx.x * 4 + wave;
  if (n >= N_NODES) return;
  const int s = segoff[n];
  const int e = segoff[n + 1];
  const int colbase = lane * V;
  float acc[V], acc2[V];
#pragma unroll
  for (int i = 0; i < V; ++i) { acc[i] = 0.f; acc2[i] = 0.f; }

  auto addrow = [&](float* a, int rid) {
    const unsigned short* yr = Y + (size_t)rid * DO + colbase;
    if constexpr (V == 4) {
      const uint2 v = *reinterpret_cast<const uint2*>(yr);
      a[0] += bflo(v.x); a[1] += bfhi(v.x);
      a[2] += bflo(v.y); a[3] += bfhi(v.y);
    } else {
      const unsigned v = *reinterpret_cast<const unsigned*>(yr);
      a[0] += bflo(v); a[1] += bfhi(v);
    }
  };

  int j = s;
  for (; j + 1 < e; j += 2) {
    const int s0 = esorted[j];
    const int s1 = esorted[j + 1];
    addrow(acc, s0);
    addrow(acc2, s1);
  }
  if (j < e) addrow(acc, esorted[j]);
  addrow(acc2, n);  // self loop

  const float sc = nisq[n];
#pragma unroll
  for (int i = 0; i < V; ++i) {
    float t = (acc[i] + acc2[i]) * sc;
    if (ADD_BIAS) t += bias[colbase + i];
    if (HAS_RES) t += resid[(size_t)n * DO + colbase + i];
    acc[i] = t;
  }
  if constexpr (OUT_BF16) {
    unsigned short* tr = (unsigned short*)Tv + (size_t)n * DO + colbase;
    if constexpr (V == 4) {
      ushort4 o;
      o.x = f2bf(acc[0]); o.y = f2bf(acc[1]); o.z = f2bf(acc[2]); o.w = f2bf(acc[3]);
      *reinterpret_cast<ushort4*>(tr) = o;
    } else {
      const unsigned o = (unsigned)f2bf(acc[0]) | ((unsigned)f2bf(acc[1]) << 16);
      *reinterpret_cast<unsigned*>(tr) = o;
    }
  } else {
    float* tr = (float*)Tv + (size_t)n * DO + colbase;
    if constexpr (V == 4) {
      float4 o; o.x = acc[0]; o.y = acc[1]; o.z = acc[2]; o.w = acc[3];
      *reinterpret_cast<float4*>(tr) = o;
    } else {
      float2 o; o.x = acc[0]; o.y = acc[1];
      *reinterpret_cast<float2*>(tr) = o;
    }
  }
}

// ---------------- column sums for BN stats ----------------
__global__ void stats_kernel(const float* __restrict__ T, float* __restrict__ colsum,
                             float* __restrict__ colsumsq, int n, int rowsPerBlock) {
  const int c = threadIdx.x;
  const int DO = blockDim.x;
  const int r0 = blockIdx.x * rowsPerBlock;
  int r1 = r0 + rowsPerBlock;
  if (r1 > n) r1 = n;
  float s = 0.f, q = 0.f;
  for (int r = r0; r < r1; ++r) {
    const float v = T[(size_t)r * DO + c];
    s += v;
    q += v * v;
  }
  atomicAdd(&colsum[c], s);
  atomicAdd(&colsumsq[c], q);
}

// ---------------- BN apply + LeakyReLU -> bf16 ----------------
__global__ void bn_lrelu_bf16_kernel(const float* __restrict__ T,
                                     const float* __restrict__ colsum,
                                     const float* __restrict__ colsumsq,
                                     const float* __restrict__ g, const float* __restrict__ be,
                                     unsigned short* __restrict__ Tb,
                                     size_t total4, unsigned domask4, float invN) {
  const size_t idx = (size_t)blockIdx.x * 256 + threadIdx.x;
  if (idx >= total4) return;
  const unsigned c = ((unsigned)idx & domask4) * 4;
  const float4 cs = *reinterpret_cast<const float4*>(&colsum[c]);
  const float4 cq = *reinterpret_cast<const float4*>(&colsumsq[c]);
  const float4 gv = *reinterpret_cast<const float4*>(&g[c]);
  const float4 bv = *reinterpret_cast<const float4*>(&be[c]);
  const float4 t = *reinterpret_cast<const float4*>(&T[idx * 4]);
  const float m0 = cs.x * invN, m1 = cs.y * invN, m2 = cs.z * invN, m3 = cs.w * invN;
  const float r0 = rsqrtf(cq.x * invN - m0 * m0 + EPS_C);
  const float r1 = rsqrtf(cq.y * invN - m1 * m1 + EPS_C);
  const float r2 = rsqrtf(cq.z * invN - m2 * m2 + EPS_C);
  const float r3 = rsqrtf(cq.w * invN - m3 * m3 + EPS_C);
  float z0 = (t.x - m0) * r0 * gv.x + bv.x; z0 = (z0 >= 0.f) ? z0 : SLOPE_C * z0;
  float z1 = (t.y - m1) * r1 * gv.y + bv.y; z1 = (z1 >= 0.f) ? z1 : SLOPE_C * z1;
  float z2 = (t.z - m2) * r2 * gv.z + bv.z; z2 = (z2 >= 0.f) ? z2 : SLOPE_C * z2;
  float z3 = (t.w - m3) * r3 * gv.w + bv.w; z3 = (z3 >= 0.f) ? z3 : SLOPE_C * z3;
  ushort4 o;
  o.x = f2bf(z0); o.y = f2bf(z1); o.z = f2bf(z2); o.w = f2bf(z3);
  *reinterpret_cast<ushort4*>(&Tb[idx * 4]) = o;
}

// ---------------- final: BN apply + LayerNorm fused (DO=128) ----------------
__global__ __launch_bounds__(256) void bn_ln_kernel(
    const float* __restrict__ T, const float* __restrict__ colsum,
    const float* __restrict__ colsumsq, const float* __restrict__ g,
    const float* __restrict__ be, const float* __restrict__ lng,
    const float* __restrict__ lnb, float* __restrict__ out, float invN) {
  const int wave = threadIdx.x >> 6;
  const int lane = threadIdx.x & 63;
  const int n = blockIdx.x * 4 + wave;
  if (n >= N_NODES) return;
  const int c = lane * 2;
  const float2 t = *reinterpret_cast<const float2*>(&T[(size_t)n * 128 + c]);
  float z[2];
#pragma unroll
  for (int k = 0; k < 2; ++k) {
    const float m = colsum[c + k] * invN;
    const float v = colsumsq[c + k] * invN - m * m;
    const float tv = (k == 0) ? t.x : t.y;
    z[k] = (tv - m) * rsqrtf(v + EPS_C) * g[c + k] + be[c + k];
  }
  float s = z[0] + z[1];
  float q = z[0] * z[0] + z[1] * z[1];
  for (int o = 32; o > 0; o >>= 1) {
    s += __shfl_xor(s, o, 64);
    q += __shfl_xor(q, o, 64);
  }
  const float mean = s * (1.f / 128.f);
  const float var = q * (1.f / 128.f) - mean * mean;
  const float rs = rsqrtf(var + EPS_C);
  float2 o2;
  o2.x = (z[0] - mean) * rs * lng[c] + lnb[c];
  o2.y = (z[1] - mean) * rs * lng[c + 1] + lnb[c + 1];
  *reinterpret_cast<float2*>(&out[(size_t)n * 128 + c]) = o2;
}

extern "C" void kernel_launch(void* const* d_in, const int* in_sizes, int n_in,
                              void* d_out, int out_size, void* d_ws, size_t ws_size,
                              hipStream_t stream) {
  const float* x = (const float*)d_in[0];
  const int* ei = (const int*)d_in[1];
  const int* srcp = ei;
  const int* dstp = ei + N_EDGES;
  const float* W1 = (const float*)d_in[2];
  const float* b1 = (const float*)d_in[3];
  const float* g1 = (const float*)d_in[4];
  const float* be1 = (const float*)d_in[5];
  const float* W2 = (const float*)d_in[6];
  const float* b2 = (const float*)d_in[7];
  const float* g2 = (const float*)d_in[8];
  const float* be2 = (const float*)d_in[9];
  const float* W3 = (const float*)d_in[10];
  const float* b3 = (const float*)d_in[11];
  const float* g3 = (const float*)d_in[12];
  const float* be3 = (const float*)d_in[13];
  const float* W4 = (const float*)d_in[14];
  const float* b4 = (const float*)d_in[15];
  const float* g4 = (const float*)d_in[16];
  const float* be4 = (const float*)d_in[17];
  const float* lng = (const float*)d_in[18];
  const float* lnb = (const float*)d_in[19];
  float* out = (float*)d_out;

  char* ws = (char*)d_ws;
  size_t off_b = 0;
  auto alloc = [&](size_t bytes) -> void* {
    void* p = (void*)(ws + off_b);
    off_b += (bytes + 255) & ~(size_t)255;
    return p;
  };
  int* hist = (int*)alloc((size_t)N_NODES * 4);
  int* segoff = (int*)alloc((size_t)(N_NODES + 1) * 4);
  int* cursor = (int*)alloc((size_t)N_NODES * 4);
  float* nisq = (float*)alloc((size_t)N_NODES * 4);
  int* esorted = (int*)alloc((size_t)N_EDGES * 4);
  int* partial = (int*)alloc(64 * 4);
  int* partialoff = (int*)alloc(64 * 4);
  float* colsum = (float*)alloc(256 * 4);
  float* colsumsq = (float*)alloc(256 * 4);
  unsigned short* Wt1 = (unsigned short*)alloc((size_t)256 * 128 * 2);
  unsigned short* Wt2 = (unsigned short*)alloc((size_t)256 * 256 * 2);
  unsigned short* Wt3 = (unsigned short*)alloc((size_t)256 * 256 * 2);
  unsigned short* Wt4 = (unsigned short*)alloc((size_t)128 * 256 * 2);
  float* T = (float*)alloc((size_t)N_NODES * 256 * 4);
  unsigned short* Tb = (unsigned short*)alloc((size_t)N_NODES * 256 * 2);
  unsigned short* Ybf = (unsigned short*)alloc((size_t)N_NODES * 256 * 2);
  // aliases into Ybf (dead before L2 gemm writes Ybf):
  unsigned short* xsb = Ybf;                                  // N x 128 bf16
  unsigned short* xaB = Ybf + (size_t)N_NODES * 128;          // N x 128 bf16

  const float invN = 1.0f / (float)N_NODES;
  const int egrid = (N_EDGES + 255) / 256;
  const int ngrid = (N_NODES + 255) / 256;
  const int aggrid = (N_NODES + 3) / 4;
  const int statgrid = (N_NODES + 127) / 128;
  const int nb = (N_NODES + 1023) / 1024;
  const dim3 mgrid256((N_NODES + 127) / 128, 4);
  const dim3 mgrid128((N_NODES + 127) / 128, 2);
  const unsigned bngrid256 = (unsigned)(((size_t)N_NODES * 64 + 255) / 256);

  // ---- degrees + dst-sorted edge list (counting sort) ----
  hipMemsetAsync(hist, 0, (size_t)N_NODES * 4, stream);
  hist_kernel<<<egrid, 256, 0, stream>>>(dstp, hist, N_EDGES);
  nisq_kernel<<<ngrid, 256, 0, stream>>>(hist, nisq, N_NODES);
  scan1_kernel<<<nb, 1024, 0, stream>>>(hist, segoff, partial, N_NODES);
  scan2_kernel<<<1, 64, 0, stream>>>(partial, partialoff, &segoff[N_NODES], nb);
  scan3_kernel<<<ngrid, 256, 0, stream>>>(segoff, cursor, partialoff, N_NODES);
  scatter_kernel<<<egrid, 256, 0, stream>>>(srcp, dstp, cursor, esorted, N_EDGES);

  // ---- weight transpose+cast ----
  wcast_kernel<<<(128 * 256 + 255) / 256, 256, 0, stream>>>(W1, Wt1, 128 * 256, 8, 255, 128);
  wcast_kernel<<<(256 * 256 + 255) / 256, 256, 0, stream>>>(W2, Wt2, 256 * 256, 8, 255, 256);
  wcast_kernel<<<(256 * 256 + 255) / 256, 256, 0, stream>>>(W3, Wt3, 256 * 256, 8, 255, 256);
  wcast_kernel<<<(256 * 128 + 255) / 256, 256, 0, stream>>>(W4, Wt4, 256 * 128, 7, 127, 256);

  // ---- Layer 1: aggregate input first (A_hat x), then MFMA GEMM 128->256 + bias ----
  scale_cast_kernel<<<(N_NODES * 32 + 255) / 256, 256, 0, stream>>>(x, nisq, xsb);
  aggregate_bf16_kernel<128, false, false, true><<<aggrid, 256, 0, stream>>>(
      xsb, segoff, esorted, nisq, nullptr, nullptr, xaB);
  gemm_mfma_kernel<false, false><<<mgrid256, 256, 0, stream>>>(xaB, Wt1, b1, T, N_NODES, 128, 256);
  hipMemsetAsync(colsum, 0, 2048, stream);
  stats_kernel<<<statgrid, 256, 0, stream>>>(T, colsum, colsumsq, N_NODES, 128);
  bn_lrelu_bf16_kernel<<<bngrid256, 256, 0, stream>>>(T, colsum, colsumsq, g1, be1, Tb,
                                                      (size_t)N_NODES * 64, 63u, invN);

  // ---- Layer 2: 256 -> 256 ----
  gemm_mfma_kernel<true, true><<<mgrid256, 256, 0, stream>>>(Tb, Wt2, nisq, Ybf, N_NODES, 256, 256);
  aggregate_bf16_kernel<256, true, false, false><<<aggrid, 256, 0, stream>>>(
      Ybf, segoff, esorted, nisq, b2, nullptr, T);
  hipMemsetAsync(colsum, 0, 2048, stream);
  stats_kernel<<<statgrid, 256, 0, stream>>>(T, colsum, colsumsq, N_NODES, 128);
  bn_lrelu_bf16_kernel<<<bngrid256, 256, 0, stream>>>(T, colsum, colsumsq, g2, be2, Tb,
                                                      (size_t)N_NODES * 64, 63u, invN);

  // ---- Layer 3: 256 -> 256 ----
  gemm_mfma_kernel<true, true><<<mgrid256, 256, 0, stream>>>(Tb, Wt3, nisq, Ybf, N_NODES, 256, 256);
  aggregate_bf16_kernel<256, true, false, false><<<aggrid, 256, 0, stream>>>(
      Ybf, segoff, esorted, nisq, b3, nullptr, T);
  hipMemsetAsync(colsum, 0, 2048, stream);
  stats_kernel<<<statgrid, 256, 0, stream>>>(T, colsum, colsumsq, N_NODES, 128);
  bn_lrelu_bf16_kernel<<<bngrid256, 256, 0, stream>>>(T, colsum, colsumsq, g3, be3, Tb,
                                                      (size_t)N_NODES * 64, 63u, invN);

  // ---- Layer 4: 256 -> 128, residual + BN + LayerNorm ----
  gemm_mfma_kernel<true, true><<<mgrid128, 256, 0, stream>>>(Tb, Wt4, nisq, Ybf, N_NODES, 256, 128);
  aggregate_bf16_kernel<128, true, true, false><<<aggrid, 256, 0, stream>>>(
      Ybf, segoff, esorted, nisq, b4, x, T);
  hipMemsetAsync(colsum, 0, 2048, stream);
  stats_kernel<<<statgrid, 128, 0, stream>>>(T, colsum, colsumsq, N_NODES, 128);
  bn_ln_kernel<<<aggrid, 256, 0, stream>>>(T, colsum, colsumsq, g4, be4, lng, lnb, out, invN);
}

// Round 4
// 589.596 us; speedup vs baseline: 1.9422x; 1.1397x over previous
//
#include <hip/hip_runtime.h>

#define N_NODES 50000
#define N_EDGES 800000
#define EPS_C 1e-5f
#define SLOPE_C 0.01f

typedef __attribute__((ext_vector_type(8))) short short8v;
typedef __attribute__((ext_vector_type(4))) float f32x4;

// ---------- bf16 helpers (RNE) ----------
__device__ __forceinline__ unsigned short f2bf(float f) {
  unsigned u = __float_as_uint(f);
  u += 0x7fffu + ((u >> 16) & 1u);
  return (unsigned short)(u >> 16);
}
__device__ __forceinline__ unsigned packbf(float a, float b) {
  return (unsigned)f2bf(a) | ((unsigned)f2bf(b) << 16);
}
__device__ __forceinline__ float bflo(unsigned u) { return __uint_as_float(u << 16); }
__device__ __forceinline__ float bfhi(unsigned u) { return __uint_as_float(u & 0xffff0000u); }

// ---------------- W transpose + cast: Wt[m][k] = bf16(W[k][m]) ----------------
__global__ void wcast_kernel(const float* __restrict__ W, unsigned short* __restrict__ Wt,
                             int total, int mshift, int mmask, int K) {
  const int idx = blockIdx.x * 256 + threadIdx.x;
  if (idx >= total) return;
  const int k = idx >> mshift;
  const int m = idx & mmask;
  Wt[(size_t)m * K + k] = f2bf(W[idx]);
}

// ---------------- MFMA GEMM (unchanged from r3) ----------------
template <bool NISQ_EPI, bool BF16OUT>
__global__ __launch_bounds__(256) void gemm_mfma_kernel(
    const unsigned short* __restrict__ A, const unsigned short* __restrict__ Wt,
    const float* __restrict__ aux, void* __restrict__ Yv,
    int Nrows, int K, int M) {
  __shared__ __align__(16) unsigned short As[128][72];
  __shared__ __align__(16) unsigned short Bs[64][72];
  const int tid = threadIdx.x;
  const int lane = tid & 63;
  const int wave = tid >> 6;
  const int wr = wave >> 1, wc = wave & 1;
  const int row0 = blockIdx.x * 128;
  const int col0 = blockIdx.y * 64;
  const int l15 = lane & 15;
  const int lhi = lane >> 4;
  f32x4 acc[4][2];
#pragma unroll
  for (int i = 0; i < 4; ++i)
#pragma unroll
    for (int j = 0; j < 2; ++j) acc[i][j] = (f32x4){0.f, 0.f, 0.f, 0.f};

  for (int k0 = 0; k0 < K; k0 += 64) {
#pragma unroll
    for (int c = 0; c < 4; ++c) {
      const int id = tid + c * 256;
      const int r = id >> 3;
      const int ck = (id & 7) * 8;
      short8v v = {};
      const int grow = row0 + r;
      if (grow < Nrows)
        v = *reinterpret_cast<const short8v*>(&A[(size_t)grow * K + k0 + ck]);
      *reinterpret_cast<short8v*>(&As[r][ck]) = v;
    }
#pragma unroll
    for (int c = 0; c < 2; ++c) {
      const int id = tid + c * 256;
      const int r = id >> 3;
      const int ck = (id & 7) * 8;
      const short8v v =
          *reinterpret_cast<const short8v*>(&Wt[(size_t)(col0 + r) * K + k0 + ck]);
      *reinterpret_cast<short8v*>(&Bs[r][ck]) = v;
    }
    __syncthreads();
    short8v bfr[2][2];
#pragma unroll
    for (int nr = 0; nr < 2; ++nr)
#pragma unroll
      for (int h = 0; h < 2; ++h)
        bfr[nr][h] = *reinterpret_cast<const short8v*>(
            &Bs[wc * 32 + nr * 16 + l15][h * 32 + lhi * 8]);
#pragma unroll
    for (int mr = 0; mr < 4; ++mr) {
#pragma unroll
      for (int h = 0; h < 2; ++h) {
        const short8v af = *reinterpret_cast<const short8v*>(
            &As[wr * 64 + mr * 16 + l15][h * 32 + lhi * 8]);
#pragma unroll
        for (int nr = 0; nr < 2; ++nr)
          acc[mr][nr] = __builtin_amdgcn_mfma_f32_16x16x32_bf16(
              af, bfr[nr][h], acc[mr][nr], 0, 0, 0);
      }
    }
    __syncthreads();
  }
#pragma unroll
  for (int mr = 0; mr < 4; ++mr) {
#pragma unroll
    for (int r = 0; r < 4; ++r) {
      const int grow = row0 + wr * 64 + mr * 16 + lhi * 4 + r;
      if (grow < Nrows) {
        if constexpr (NISQ_EPI) {
          const float s = aux[grow];
          unsigned short* Y = (unsigned short*)Yv;
#pragma unroll
          for (int nr = 0; nr < 2; ++nr) {
            const int gcol = col0 + wc * 32 + nr * 16 + l15;
            Y[(size_t)grow * M + gcol] = f2bf(acc[mr][nr][r] * s);
          }
        } else {
          float* Y = (float*)Yv;
#pragma unroll
          for (int nr = 0; nr < 2; ++nr) {
            const int gcol = col0 + wc * 32 + nr * 16 + l15;
            Y[(size_t)grow * M + gcol] = acc[mr][nr][r] + aux[gcol];
          }
        }
      }
    }
  }
}

// ---------------- degree histogram / nisq ----------------
__global__ void hist_kernel(const int* __restrict__ dst, int* __restrict__ hist, int E) {
  const int e = blockIdx.x * 256 + threadIdx.x;
  if (e < E) atomicAdd(&hist[dst[e]], 1);
}

__global__ void nisq_kernel(const int* __restrict__ hist, float* __restrict__ nisq, int n) {
  const int i = blockIdx.x * 256 + threadIdx.x;
  if (i < n) nisq[i] = rsqrtf((float)hist[i] + 1.0f);
}

// ---------------- two-level exclusive scan ----------------
__global__ __launch_bounds__(1024) void scan1_kernel(
    const int* __restrict__ hist, int* __restrict__ off, int* __restrict__ partial, int n) {
  __shared__ int tmp[1024];
  const int tid = threadIdx.x;
  const int i = blockIdx.x * 1024 + tid;
  const int v = (i < n) ? hist[i] : 0;
  tmp[tid] = v;
  __syncthreads();
  int x = v;
  for (int o = 1; o < 1024; o <<= 1) {
    const int y = (tid >= o) ? tmp[tid - o] : 0;
    __syncthreads();
    x += y;
    tmp[tid] = x;
    __syncthreads();
  }
  if (i < n) off[i] = x - v;
  if (tid == 1023) partial[blockIdx.x] = x;
}

__global__ __launch_bounds__(64) void scan2_kernel(
    const int* __restrict__ partial, int* __restrict__ partialoff,
    int* __restrict__ offN, int nb) {
  const int tid = threadIdx.x;
  const int v = (tid < nb) ? partial[tid] : 0;
  int x = v;
  for (int o = 1; o < 64; o <<= 1) {
    const int y = __shfl_up(x, o, 64);
    if (tid >= o) x += y;
  }
  if (tid < nb) partialoff[tid] = x - v;
  if (tid == 63) *offN = x;
}

__global__ void scan3_kernel(int* __restrict__ off, int* __restrict__ cursor,
                             const int* __restrict__ partialoff, int n) {
  const int i = blockIdx.x * 256 + threadIdx.x;
  if (i < n) {
    const int o = off[i] + partialoff[i >> 10];
    off[i] = o;
    cursor[i] = o;
  }
}

// ---------------- scatter edges into dst-sorted order ----------------
__global__ void scatter_kernel(const int* __restrict__ src, const int* __restrict__ dst,
                               int* __restrict__ cursor, int* __restrict__ esorted, int E) {
  const int e = blockIdx.x * 256 + threadIdx.x;
  if (e < E) {
    const int p = atomicAdd(&cursor[dst[e]], 1);
    esorted[p] = src[e];
  }
}

// ---------------- scale+cast: xs = bf16(x * nisq[row]), DI=128 ----------------
__global__ void scale_cast_kernel(const float* __restrict__ x,
                                  const float* __restrict__ nisq,
                                  unsigned short* __restrict__ xs) {
  const int idx = blockIdx.x * 256 + threadIdx.x;
  if (idx >= N_NODES * 32) return;
  const int row = idx >> 5;
  const int c = (idx & 31) * 4;
  const float s = nisq[row];
  const float4 v = *reinterpret_cast<const float4*>(&x[(size_t)row * 128 + c]);
  ushort4 o;
  o.x = f2bf(v.x * s); o.y = f2bf(v.y * s);
  o.z = f2bf(v.z * s); o.w = f2bf(v.w * s);
  *reinterpret_cast<ushort4*>(&xs[(size_t)row * 128 + c]) = o;
}

// ---------------- aggregation v2: half-wave split, 16B/lane, fused stats ----------------
template <int DO, bool ADD_BIAS, bool HAS_RES, bool OUT_BF16, bool STATS>
__global__ __launch_bounds__(256) void aggregate2_kernel(
    const unsigned short* __restrict__ Y, const int* __restrict__ segoff,
    const int* __restrict__ esorted, const float* __restrict__ nisq,
    const float* __restrict__ bias, const float* __restrict__ resid,
    void* __restrict__ Tv, float* __restrict__ split) {
  constexpr int V2 = DO / 32;  // bf16 elems per lane (128: 4, 256: 8)
  const int wave = threadIdx.x >> 6;
  const int lane = threadIdx.x & 63;
  const int half = lane >> 5;
  const int l31 = lane & 31;
  const int n = blockIdx.x * 4 + wave;
  const int colbase = l31 * V2;
  float a0[V2], a1[V2], vals[V2];
#pragma unroll
  for (int i = 0; i < V2; ++i) { a0[i] = 0.f; a1[i] = 0.f; vals[i] = 0.f; }
  const bool valid = (n < N_NODES);
  if (valid) {
    const int s = segoff[n];
    const int e = segoff[n + 1];
    auto addrow = [&](float* a, int rid) {
      const unsigned short* yr = Y + (size_t)rid * DO + colbase;
      if constexpr (V2 == 8) {
        const uint4 v = *reinterpret_cast<const uint4*>(yr);
        a[0] += bflo(v.x); a[1] += bfhi(v.x);
        a[2] += bflo(v.y); a[3] += bfhi(v.y);
        a[4] += bflo(v.z); a[5] += bfhi(v.z);
        a[6] += bflo(v.w); a[7] += bfhi(v.w);
      } else {
        const uint2 v = *reinterpret_cast<const uint2*>(yr);
        a[0] += bflo(v.x); a[1] += bfhi(v.x);
        a[2] += bflo(v.y); a[3] += bfhi(v.y);
      }
    };
    // half h consumes edges s+h, s+h+2, ... (2-deep unroll -> 4 rows in flight/wave)
    int j = s + half;
    for (; j + 2 < e; j += 4) {
      const int i0 = esorted[j];
      const int i1 = esorted[j + 2];
      addrow(a0, i0);
      addrow(a1, i1);
    }
    if (j < e) addrow(a0, esorted[j]);
    if (half == 0) addrow(a1, n);  // self loop once
    const float sc = nisq[n];
#pragma unroll
    for (int i = 0; i < V2; ++i) {
      float t = a0[i] + a1[i];
      t += __shfl_xor(t, 32, 64);
      t *= sc;
      if (half == 0) {
        if (ADD_BIAS) t += bias[colbase + i];
        if (HAS_RES) t += resid[(size_t)n * DO + colbase + i];
      }
      vals[i] = t;
    }
    if (half == 0) {
      if constexpr (OUT_BF16) {
        unsigned short* tr = (unsigned short*)Tv + (size_t)n * DO + colbase;
        if constexpr (V2 == 8) {
          uint4 o;
          o.x = packbf(vals[0], vals[1]); o.y = packbf(vals[2], vals[3]);
          o.z = packbf(vals[4], vals[5]); o.w = packbf(vals[6], vals[7]);
          *reinterpret_cast<uint4*>(tr) = o;
        } else {
          uint2 o;
          o.x = packbf(vals[0], vals[1]); o.y = packbf(vals[2], vals[3]);
          *reinterpret_cast<uint2*>(tr) = o;
        }
      } else {
        float* tr = (float*)Tv + (size_t)n * DO + colbase;
        if constexpr (V2 == 8) {
          float4 o0 = {vals[0], vals[1], vals[2], vals[3]};
          float4 o1 = {vals[4], vals[5], vals[6], vals[7]};
          *reinterpret_cast<float4*>(tr) = o0;
          *reinterpret_cast<float4*>(tr + 4) = o1;
        } else {
          float4 o = {vals[0], vals[1], vals[2], vals[3]};
          *reinterpret_cast<float4*>(tr) = o;
        }
      }
    }
  }
  if constexpr (STATS) {
    __shared__ float spart[4][DO];
    if (half == 0) {
#pragma unroll
      for (int i = 0; i < V2; ++i) spart[wave][colbase + i] = vals[i];
    }
    __syncthreads();
    const int tid = threadIdx.x;
    if (tid < DO) {
      float s = 0.f, q = 0.f;
#pragma unroll
      for (int w = 0; w < 4; ++w) {
        const float v = spart[w][tid];
        s += v;
        q += v * v;
      }
      const int sb = (blockIdx.x & 63) * 2 * DO;
      atomicAdd(&split[sb + tid], s);
      atomicAdd(&split[sb + DO + tid], q);
    }
  }
}

// ---------------- reduce 64-way split stats ----------------
__global__ void reduce_stats_kernel(const float* __restrict__ split,
                                    float* __restrict__ colsum,
                                    float* __restrict__ colsumsq, int DO) {
  const int c = threadIdx.x;
  if (c >= DO) return;
  float s = 0.f, q = 0.f;
  for (int k = 0; k < 64; ++k) {
    s += split[k * 2 * DO + c];
    q += split[k * 2 * DO + DO + c];
  }
  colsum[c] = s;
  colsumsq[c] = q;
}

// ---------------- column sums for BN stats (L1 only, f32 input) ----------------
__global__ void stats_kernel(const float* __restrict__ T, float* __restrict__ colsum,
                             float* __restrict__ colsumsq, int n, int rowsPerBlock) {
  const int c = threadIdx.x;
  const int DO = blockDim.x;
  const int r0 = blockIdx.x * rowsPerBlock;
  int r1 = r0 + rowsPerBlock;
  if (r1 > n) r1 = n;
  float s = 0.f, q = 0.f;
  for (int r = r0; r < r1; ++r) {
    const float v = T[(size_t)r * DO + c];
    s += v;
    q += v * v;
  }
  atomicAdd(&colsum[c], s);
  atomicAdd(&colsumsq[c], q);
}

// ---------------- BN apply + LeakyReLU, f32 in -> bf16 out (L1) ----------------
__global__ void bn_lrelu_bf16_kernel(const float* __restrict__ T,
                                     const float* __restrict__ colsum,
                                     const float* __restrict__ colsumsq,
                                     const float* __restrict__ g, const float* __restrict__ be,
                                     unsigned short* __restrict__ Tb,
                                     size_t total4, unsigned domask4, float invN) {
  const size_t idx = (size_t)blockIdx.x * 256 + threadIdx.x;
  if (idx >= total4) return;
  const unsigned c = ((unsigned)idx & domask4) * 4;
  const float4 cs = *reinterpret_cast<const float4*>(&colsum[c]);
  const float4 cq = *reinterpret_cast<const float4*>(&colsumsq[c]);
  const float4 gv = *reinterpret_cast<const float4*>(&g[c]);
  const float4 bv = *reinterpret_cast<const float4*>(&be[c]);
  const float4 t = *reinterpret_cast<const float4*>(&T[idx * 4]);
  const float m0 = cs.x * invN, m1 = cs.y * invN, m2 = cs.z * invN, m3 = cs.w * invN;
  const float r0 = rsqrtf(cq.x * invN - m0 * m0 + EPS_C);
  const float r1 = rsqrtf(cq.y * invN - m1 * m1 + EPS_C);
  const float r2 = rsqrtf(cq.z * invN - m2 * m2 + EPS_C);
  const float r3 = rsqrtf(cq.w * invN - m3 * m3 + EPS_C);
  float z0 = (t.x - m0) * r0 * gv.x + bv.x; z0 = (z0 >= 0.f) ? z0 : SLOPE_C * z0;
  float z1 = (t.y - m1) * r1 * gv.y + bv.y; z1 = (z1 >= 0.f) ? z1 : SLOPE_C * z1;
  float z2 = (t.z - m2) * r2 * gv.z + bv.z; z2 = (z2 >= 0.f) ? z2 : SLOPE_C * z2;
  float z3 = (t.w - m3) * r3 * gv.w + bv.w; z3 = (z3 >= 0.f) ? z3 : SLOPE_C * z3;
  ushort4 o;
  o.x = f2bf(z0); o.y = f2bf(z1); o.z = f2bf(z2); o.w = f2bf(z3);
  *reinterpret_cast<ushort4*>(&Tb[idx * 4]) = o;
}

// ---------------- BN apply + LeakyReLU, bf16 in-place (L2/L3) ----------------
__global__ void bn_lrelu_ip_kernel(unsigned short* __restrict__ Tb,
                                   const float* __restrict__ colsum,
                                   const float* __restrict__ colsumsq,
                                   const float* __restrict__ g, const float* __restrict__ be,
                                   size_t total8, unsigned mask8, float invN) {
  const size_t idx = (size_t)blockIdx.x * 256 + threadIdx.x;
  if (idx >= total8) return;
  const unsigned c = ((unsigned)idx & mask8) * 8;
  uint4 v = *reinterpret_cast<uint4*>(&Tb[idx * 8]);
  float z[8] = {bflo(v.x), bfhi(v.x), bflo(v.y), bfhi(v.y),
                bflo(v.z), bfhi(v.z), bflo(v.w), bfhi(v.w)};
  const float4 cs0 = *reinterpret_cast<const float4*>(&colsum[c]);
  const float4 cs1 = *reinterpret_cast<const float4*>(&colsum[c + 4]);
  const float4 cq0 = *reinterpret_cast<const float4*>(&colsumsq[c]);
  const float4 cq1 = *reinterpret_cast<const float4*>(&colsumsq[c + 4]);
  const float4 gv0 = *reinterpret_cast<const float4*>(&g[c]);
  const float4 gv1 = *reinterpret_cast<const float4*>(&g[c + 4]);
  const float4 bv0 = *reinterpret_cast<const float4*>(&be[c]);
  const float4 bv1 = *reinterpret_cast<const float4*>(&be[c + 4]);
  const float css[8] = {cs0.x, cs0.y, cs0.z, cs0.w, cs1.x, cs1.y, cs1.z, cs1.w};
  const float cqq[8] = {cq0.x, cq0.y, cq0.z, cq0.w, cq1.x, cq1.y, cq1.z, cq1.w};
  const float ggg[8] = {gv0.x, gv0.y, gv0.z, gv0.w, gv1.x, gv1.y, gv1.z, gv1.w};
  const float bbb[8] = {bv0.x, bv0.y, bv0.z, bv0.w, bv1.x, bv1.y, bv1.z, bv1.w};
#pragma unroll
  for (int k = 0; k < 8; ++k) {
    const float m = css[k] * invN;
    const float rs = rsqrtf(cqq[k] * invN - m * m + EPS_C);
    float zz = (z[k] - m) * rs * ggg[k] + bbb[k];
    z[k] = (zz >= 0.f) ? zz : SLOPE_C * zz;
  }
  v.x = packbf(z[0], z[1]); v.y = packbf(z[2], z[3]);
  v.z = packbf(z[4], z[5]); v.w = packbf(z[6], z[7]);
  *reinterpret_cast<uint4*>(&Tb[idx * 8]) = v;
}

// ---------------- final: BN apply + LayerNorm fused (DO=128) ----------------
__global__ __launch_bounds__(256) void bn_ln_kernel(
    const float* __restrict__ T, const float* __restrict__ colsum,
    const float* __restrict__ colsumsq, const float* __restrict__ g,
    const float* __restrict__ be, const float* __restrict__ lng,
    const float* __restrict__ lnb, float* __restrict__ out, float invN) {
  const int wave = threadIdx.x >> 6;
  const int lane = threadIdx.x & 63;
  const int n = blockIdx.x * 4 + wave;
  if (n >= N_NODES) return;
  const int c = lane * 2;
  const float2 t = *reinterpret_cast<const float2*>(&T[(size_t)n * 128 + c]);
  float z[2];
#pragma unroll
  for (int k = 0; k < 2; ++k) {
    const float m = colsum[c + k] * invN;
    const float v = colsumsq[c + k] * invN - m * m;
    const float tv = (k == 0) ? t.x : t.y;
    z[k] = (tv - m) * rsqrtf(v + EPS_C) * g[c + k] + be[c + k];
  }
  float s = z[0] + z[1];
  float q = z[0] * z[0] + z[1] * z[1];
  for (int o = 32; o > 0; o >>= 1) {
    s += __shfl_xor(s, o, 64);
    q += __shfl_xor(q, o, 64);
  }
  const float mean = s * (1.f / 128.f);
  const float var = q * (1.f / 128.f) - mean * mean;
  const float rs = rsqrtf(var + EPS_C);
  float2 o2;
  o2.x = (z[0] - mean) * rs * lng[c] + lnb[c];
  o2.y = (z[1] - mean) * rs * lng[c + 1] + lnb[c + 1];
  *reinterpret_cast<float2*>(&out[(size_t)n * 128 + c]) = o2;
}

extern "C" void kernel_launch(void* const* d_in, const int* in_sizes, int n_in,
                              void* d_out, int out_size, void* d_ws, size_t ws_size,
                              hipStream_t stream) {
  const float* x = (const float*)d_in[0];
  const int* ei = (const int*)d_in[1];
  const int* srcp = ei;
  const int* dstp = ei + N_EDGES;
  const float* W1 = (const float*)d_in[2];
  const float* b1 = (const float*)d_in[3];
  const float* g1 = (const float*)d_in[4];
  const float* be1 = (const float*)d_in[5];
  const float* W2 = (const float*)d_in[6];
  const float* b2 = (const float*)d_in[7];
  const float* g2 = (const float*)d_in[8];
  const float* be2 = (const float*)d_in[9];
  const float* W3 = (const float*)d_in[10];
  const float* b3 = (const float*)d_in[11];
  const float* g3 = (const float*)d_in[12];
  const float* be3 = (const float*)d_in[13];
  const float* W4 = (const float*)d_in[14];
  const float* b4 = (const float*)d_in[15];
  const float* g4 = (const float*)d_in[16];
  const float* be4 = (const float*)d_in[17];
  const float* lng = (const float*)d_in[18];
  const float* lnb = (const float*)d_in[19];
  float* out = (float*)d_out;

  char* ws = (char*)d_ws;
  size_t off_b = 0;
  auto alloc = [&](size_t bytes) -> void* {
    void* p = (void*)(ws + off_b);
    off_b += (bytes + 255) & ~(size_t)255;
    return p;
  };
  int* hist = (int*)alloc((size_t)N_NODES * 4);
  int* segoff = (int*)alloc((size_t)(N_NODES + 1) * 4);
  int* cursor = (int*)alloc((size_t)N_NODES * 4);
  float* nisq = (float*)alloc((size_t)N_NODES * 4);
  int* esorted = (int*)alloc((size_t)N_EDGES * 4);
  int* partial = (int*)alloc(64 * 4);
  int* partialoff = (int*)alloc(64 * 4);
  float* colsum = (float*)alloc(256 * 4);
  float* colsumsq = (float*)alloc(256 * 4);
  float* split = (float*)alloc((size_t)64 * 2 * 256 * 4);  // 128 KB
  unsigned short* Wt1 = (unsigned short*)alloc((size_t)256 * 128 * 2);
  unsigned short* Wt2 = (unsigned short*)alloc((size_t)256 * 256 * 2);
  unsigned short* Wt3 = (unsigned short*)alloc((size_t)256 * 256 * 2);
  unsigned short* Wt4 = (unsigned short*)alloc((size_t)128 * 256 * 2);
  float* T = (float*)alloc((size_t)N_NODES * 256 * 4);
  unsigned short* B1 = (unsigned short*)alloc((size_t)N_NODES * 256 * 2);
  unsigned short* B2 = (unsigned short*)alloc((size_t)N_NODES * 256 * 2);
  unsigned short* Ybf = (unsigned short*)alloc((size_t)N_NODES * 256 * 2);
  // aliases into Ybf (dead before L2 gemm writes Ybf):
  unsigned short* xsb = Ybf;                          // N x 128 bf16
  unsigned short* xaB = Ybf + (size_t)N_NODES * 128;  // N x 128 bf16

  const float invN = 1.0f / (float)N_NODES;
  const int egrid = (N_EDGES + 255) / 256;
  const int ngrid = (N_NODES + 255) / 256;
  const int aggrid = (N_NODES + 3) / 4;
  const int statgrid = (N_NODES + 127) / 128;
  const int nb = (N_NODES + 1023) / 1024;
  const dim3 mgrid256((N_NODES + 127) / 128, 4);
  const dim3 mgrid128((N_NODES + 127) / 128, 2);
  const unsigned bngrid_f32 = (unsigned)(((size_t)N_NODES * 64 + 255) / 256);
  const unsigned bngrid_ip = (unsigned)(((size_t)N_NODES * 32 + 255) / 256);

  // ---- degrees + dst-sorted edge list (counting sort) ----
  hipMemsetAsync(hist, 0, (size_t)N_NODES * 4, stream);
  hist_kernel<<<egrid, 256, 0, stream>>>(dstp, hist, N_EDGES);
  nisq_kernel<<<ngrid, 256, 0, stream>>>(hist, nisq, N_NODES);
  scan1_kernel<<<nb, 1024, 0, stream>>>(hist, segoff, partial, N_NODES);
  scan2_kernel<<<1, 64, 0, stream>>>(partial, partialoff, &segoff[N_NODES], nb);
  scan3_kernel<<<ngrid, 256, 0, stream>>>(segoff, cursor, partialoff, N_NODES);
  scatter_kernel<<<egrid, 256, 0, stream>>>(srcp, dstp, cursor, esorted, N_EDGES);

  // ---- weight transpose+cast ----
  wcast_kernel<<<(128 * 256 + 255) / 256, 256, 0, stream>>>(W1, Wt1, 128 * 256, 8, 255, 128);
  wcast_kernel<<<(256 * 256 + 255) / 256, 256, 0, stream>>>(W2, Wt2, 256 * 256, 8, 255, 256);
  wcast_kernel<<<(256 * 256 + 255) / 256, 256, 0, stream>>>(W3, Wt3, 256 * 256, 8, 255, 256);
  wcast_kernel<<<(256 * 128 + 255) / 256, 256, 0, stream>>>(W4, Wt4, 256 * 128, 7, 127, 256);

  // ---- Layer 1: aggregate input (A_hat x), then MFMA GEMM 128->256 + bias ----
  scale_cast_kernel<<<(N_NODES * 32 + 255) / 256, 256, 0, stream>>>(x, nisq, xsb);
  aggregate2_kernel<128, false, false, true, false><<<aggrid, 256, 0, stream>>>(
      xsb, segoff, esorted, nisq, nullptr, nullptr, xaB, nullptr);
  gemm_mfma_kernel<false, false><<<mgrid256, 256, 0, stream>>>(xaB, Wt1, b1, T, N_NODES, 128, 256);
  hipMemsetAsync(colsum, 0, 2048, stream);
  stats_kernel<<<statgrid, 256, 0, stream>>>(T, colsum, colsumsq, N_NODES, 128);
  bn_lrelu_bf16_kernel<<<bngrid_f32, 256, 0, stream>>>(T, colsum, colsumsq, g1, be1, B1,
                                                       (size_t)N_NODES * 64, 63u, invN);

  // ---- Layer 2: 256 -> 256 ----
  gemm_mfma_kernel<true, true><<<mgrid256, 256, 0, stream>>>(B1, Wt2, nisq, Ybf, N_NODES, 256, 256);
  hipMemsetAsync(split, 0, (size_t)64 * 2 * 256 * 4, stream);
  aggregate2_kernel<256, true, false, true, true><<<aggrid, 256, 0, stream>>>(
      Ybf, segoff, esorted, nisq, b2, nullptr, B2, split);
  reduce_stats_kernel<<<1, 256, 0, stream>>>(split, colsum, colsumsq, 256);
  bn_lrelu_ip_kernel<<<bngrid_ip, 256, 0, stream>>>(B2, colsum, colsumsq, g2, be2,
                                                    (size_t)N_NODES * 32, 31u, invN);

  // ---- Layer 3: 256 -> 256 ----
  gemm_mfma_kernel<true, true><<<mgrid256, 256, 0, stream>>>(B2, Wt3, nisq, Ybf, N_NODES, 256, 256);
  hipMemsetAsync(split, 0, (size_t)64 * 2 * 256 * 4, stream);
  aggregate2_kernel<256, true, false, true, true><<<aggrid, 256, 0, stream>>>(
      Ybf, segoff, esorted, nisq, b3, nullptr, B1, split);
  reduce_stats_kernel<<<1, 256, 0, stream>>>(split, colsum, colsumsq, 256);
  bn_lrelu_ip_kernel<<<bngrid_ip, 256, 0, stream>>>(B1, colsum, colsumsq, g3, be3,
                                                    (size_t)N_NODES * 32, 31u, invN);

  // ---- Layer 4: 256 -> 128, residual + BN + LayerNorm ----
  gemm_mfma_kernel<true, true><<<mgrid128, 256, 0, stream>>>(B1, Wt4, nisq, Ybf, N_NODES, 256, 128);
  hipMemsetAsync(split, 0, (size_t)64 * 2 * 128 * 4, stream);
  aggregate2_kernel<128, true, true, false, true><<<aggrid, 256, 0, stream>>>(
      Ybf, segoff, esorted, nisq, b4, x, T, split);
  reduce_stats_kernel<<<1, 128, 0, stream>>>(split, colsum, colsumsq, 128);
  bn_ln_kernel<<<aggrid, 256, 0, stream>>>(T, colsum, colsumsq, g4, be4, lng, lnb, out, invN);
}

// Round 5
// 555.801 us; speedup vs baseline: 2.0603x; 1.0608x over previous
//
#include <hip/hip_runtime.h>

#define N_NODES 50000
#define N_EDGES 800000
#define EPS_C 1e-5f
#define SLOPE_C 0.01f

typedef __attribute__((ext_vector_type(8))) short short8v;
typedef __attribute__((ext_vector_type(4))) float f32x4;

// ---------- bf16 helpers (RNE) ----------
__device__ __forceinline__ unsigned short f2bf(float f) {
  unsigned u = __float_as_uint(f);
  u += 0x7fffu + ((u >> 16) & 1u);
  return (unsigned short)(u >> 16);
}
__device__ __forceinline__ unsigned packbf(float a, float b) {
  return (unsigned)f2bf(a) | ((unsigned)f2bf(b) << 16);
}
__device__ __forceinline__ float bflo(unsigned u) { return __uint_as_float(u << 16); }
__device__ __forceinline__ float bfhi(unsigned u) { return __uint_as_float(u & 0xffff0000u); }

// ---------------- W transpose + cast: Wt[m][k] = bf16(W[k][m]) ----------------
__global__ void wcast_kernel(const float* __restrict__ W, unsigned short* __restrict__ Wt,
                             int total, int mshift, int mmask, int K) {
  const int idx = blockIdx.x * 256 + threadIdx.x;
  if (idx >= total) return;
  const int k = idx >> mshift;
  const int m = idx & mmask;
  Wt[(size_t)m * K + k] = f2bf(W[idx]);
}

// ---------------- MFMA GEMM ----------------
// MODE 0: Yb = bf16(A·Wt^T)                       (L4: nisq already folded into A's table)
// MODE 1: Yb = bf16(A·Wt^T + bias), fused col stats (L1/L2/L3)
template <int MODE>
__global__ __launch_bounds__(256) void gemm_mfma_kernel(
    const unsigned short* __restrict__ A, const unsigned short* __restrict__ Wt,
    const float* __restrict__ bias, unsigned short* __restrict__ Yb,
    float* __restrict__ colsum, float* __restrict__ colsumsq,
    int Nrows, int K, int M) {
  __shared__ __align__(16) unsigned short As[128][72];
  __shared__ __align__(16) unsigned short Bs[64][72];
  __shared__ float sred[2][64][8];
  const int tid = threadIdx.x;
  const int lane = tid & 63;
  const int wave = tid >> 6;
  const int wr = wave >> 1, wc = wave & 1;
  const int row0 = blockIdx.x * 128;
  const int col0 = blockIdx.y * 64;
  const int l15 = lane & 15;
  const int lhi = lane >> 4;
  f32x4 acc[4][2];
#pragma unroll
  for (int i = 0; i < 4; ++i)
#pragma unroll
    for (int j = 0; j < 2; ++j) acc[i][j] = (f32x4){0.f, 0.f, 0.f, 0.f};

  for (int k0 = 0; k0 < K; k0 += 64) {
#pragma unroll
    for (int c = 0; c < 4; ++c) {
      const int id = tid + c * 256;
      const int r = id >> 3;
      const int ck = (id & 7) * 8;
      short8v v = {};
      const int grow = row0 + r;
      if (grow < Nrows)
        v = *reinterpret_cast<const short8v*>(&A[(size_t)grow * K + k0 + ck]);
      *reinterpret_cast<short8v*>(&As[r][ck]) = v;
    }
#pragma unroll
    for (int c = 0; c < 2; ++c) {
      const int id = tid + c * 256;
      const int r = id >> 3;
      const int ck = (id & 7) * 8;
      const short8v v =
          *reinterpret_cast<const short8v*>(&Wt[(size_t)(col0 + r) * K + k0 + ck]);
      *reinterpret_cast<short8v*>(&Bs[r][ck]) = v;
    }
    __syncthreads();
    short8v bfr[2][2];
#pragma unroll
    for (int nr = 0; nr < 2; ++nr)
#pragma unroll
      for (int h = 0; h < 2; ++h)
        bfr[nr][h] = *reinterpret_cast<const short8v*>(
            &Bs[wc * 32 + nr * 16 + l15][h * 32 + lhi * 8]);
#pragma unroll
    for (int mr = 0; mr < 4; ++mr) {
#pragma unroll
      for (int h = 0; h < 2; ++h) {
        const short8v af = *reinterpret_cast<const short8v*>(
            &As[wr * 64 + mr * 16 + l15][h * 32 + lhi * 8]);
#pragma unroll
        for (int nr = 0; nr < 2; ++nr)
          acc[mr][nr] = __builtin_amdgcn_mfma_f32_16x16x32_bf16(
              af, bfr[nr][h], acc[mr][nr], 0, 0, 0);
      }
    }
    __syncthreads();
  }
  // epilogue
  float bcol[2] = {0.f, 0.f};
  if constexpr (MODE == 1) {
#pragma unroll
    for (int nr = 0; nr < 2; ++nr) bcol[nr] = bias[col0 + wc * 32 + nr * 16 + l15];
  }
  float s_c[2] = {0.f, 0.f}, q_c[2] = {0.f, 0.f};
#pragma unroll
  for (int mr = 0; mr < 4; ++mr) {
#pragma unroll
    for (int r = 0; r < 4; ++r) {
      const int grow = row0 + wr * 64 + mr * 16 + lhi * 4 + r;
      const bool ok = (grow < Nrows);
#pragma unroll
      for (int nr = 0; nr < 2; ++nr) {
        const int gcol = col0 + wc * 32 + nr * 16 + l15;
        float v = acc[mr][nr][r] + bcol[nr];
        if (ok) {
          Yb[(size_t)grow * M + gcol] = f2bf(v);
          if constexpr (MODE == 1) {
            s_c[nr] += v;
            q_c[nr] += v * v;
          }
        }
      }
    }
  }
  if constexpr (MODE == 1) {
    const int contrib = wr * 4 + lhi;
#pragma unroll
    for (int nr = 0; nr < 2; ++nr) {
      const int cl = wc * 32 + nr * 16 + l15;
      sred[0][cl][contrib] = s_c[nr];
      sred[1][cl][contrib] = q_c[nr];
    }
    __syncthreads();
    if (tid < 128) {
      const int which = tid >> 6;   // 0: sum, 1: sumsq
      const int cl = tid & 63;
      float acc8 = 0.f;
#pragma unroll
      for (int k = 0; k < 8; ++k) acc8 += sred[which][cl][k];
      float* dstp = which ? colsumsq : colsum;
      atomicAdd(&dstp[col0 + cl], acc8);
    }
  }
}

// ---------------- degree histogram / nisq ----------------
__global__ void hist_kernel(const int* __restrict__ dst, int* __restrict__ hist, int E) {
  const int e = blockIdx.x * 256 + threadIdx.x;
  if (e < E) atomicAdd(&hist[dst[e]], 1);
}

__global__ void nisq_kernel(const int* __restrict__ hist, float* __restrict__ nisq, int n) {
  const int i = blockIdx.x * 256 + threadIdx.x;
  if (i < n) nisq[i] = rsqrtf((float)hist[i] + 1.0f);
}

// ---------------- two-level exclusive scan ----------------
__global__ __launch_bounds__(1024) void scan1_kernel(
    const int* __restrict__ hist, int* __restrict__ off, int* __restrict__ partial, int n) {
  __shared__ int tmp[1024];
  const int tid = threadIdx.x;
  const int i = blockIdx.x * 1024 + tid;
  const int v = (i < n) ? hist[i] : 0;
  tmp[tid] = v;
  __syncthreads();
  int x = v;
  for (int o = 1; o < 1024; o <<= 1) {
    const int y = (tid >= o) ? tmp[tid - o] : 0;
    __syncthreads();
    x += y;
    tmp[tid] = x;
    __syncthreads();
  }
  if (i < n) off[i] = x - v;
  if (tid == 1023) partial[blockIdx.x] = x;
}

__global__ __launch_bounds__(64) void scan2_kernel(
    const int* __restrict__ partial, int* __restrict__ partialoff,
    int* __restrict__ offN, int nb) {
  const int tid = threadIdx.x;
  const int v = (tid < nb) ? partial[tid] : 0;
  int x = v;
  for (int o = 1; o < 64; o <<= 1) {
    const int y = __shfl_up(x, o, 64);
    if (tid >= o) x += y;
  }
  if (tid < nb) partialoff[tid] = x - v;
  if (tid == 63) *offN = x;
}

__global__ void scan3_kernel(int* __restrict__ off, int* __restrict__ cursor,
                             const int* __restrict__ partialoff, int n) {
  const int i = blockIdx.x * 256 + threadIdx.x;
  if (i < n) {
    const int o = off[i] + partialoff[i >> 10];
    off[i] = o;
    cursor[i] = o;
  }
}

// ---------------- scatter edges into dst-sorted order ----------------
__global__ void scatter_kernel(const int* __restrict__ src, const int* __restrict__ dst,
                               int* __restrict__ cursor, int* __restrict__ esorted, int E) {
  const int e = blockIdx.x * 256 + threadIdx.x;
  if (e < E) {
    const int p = atomicAdd(&cursor[dst[e]], 1);
    esorted[p] = src[e];
  }
}

// ---------------- scale+cast: xs = bf16(x * nisq[row]), DI=128 ----------------
__global__ void scale_cast_kernel(const float* __restrict__ x,
                                  const float* __restrict__ nisq,
                                  unsigned short* __restrict__ xs) {
  const int idx = blockIdx.x * 256 + threadIdx.x;
  if (idx >= N_NODES * 32) return;
  const int row = idx >> 5;
  const int c = (idx & 31) * 4;
  const float s = nisq[row];
  const float4 v = *reinterpret_cast<const float4*>(&x[(size_t)row * 128 + c]);
  ushort4 o;
  o.x = f2bf(v.x * s); o.y = f2bf(v.y * s);
  o.z = f2bf(v.z * s); o.w = f2bf(v.w * s);
  *reinterpret_cast<ushort4*>(&xs[(size_t)row * 128 + c]) = o;
}

// ---------------- pure gather aggregation (half-wave, 16B/lane for DO=256) ----------------
template <int DO, bool ADD_BIAS, bool HAS_RES, bool OUT_BF16>
__global__ __launch_bounds__(256) void aggregate3_kernel(
    const unsigned short* __restrict__ Y, const int* __restrict__ segoff,
    const int* __restrict__ esorted, const float* __restrict__ nisq,
    const float* __restrict__ bias, const float* __restrict__ resid,
    void* __restrict__ Tv) {
  constexpr int V2 = DO / 32;  // bf16 elems per lane per row (128: 4, 256: 8)
  const int wave = threadIdx.x >> 6;
  const int lane = threadIdx.x & 63;
  const int half = lane >> 5;
  const int l31 = lane & 31;
  const int n = blockIdx.x * 4 + wave;
  if (n >= N_NODES) return;
  const int colbase = l31 * V2;
  float a0[V2], a1[V2];
#pragma unroll
  for (int i = 0; i < V2; ++i) { a0[i] = 0.f; a1[i] = 0.f; }
  const int s = segoff[n];
  const int e = segoff[n + 1];
  auto addrow = [&](float* a, int rid) {
    const unsigned short* yr = Y + (size_t)rid * DO + colbase;
    if constexpr (V2 == 8) {
      const uint4 v = *reinterpret_cast<const uint4*>(yr);
      a[0] += bflo(v.x); a[1] += bfhi(v.x);
      a[2] += bflo(v.y); a[3] += bfhi(v.y);
      a[4] += bflo(v.z); a[5] += bfhi(v.z);
      a[6] += bflo(v.w); a[7] += bfhi(v.w);
    } else {
      const uint2 v = *reinterpret_cast<const uint2*>(yr);
      a[0] += bflo(v.x); a[1] += bfhi(v.x);
      a[2] += bflo(v.y); a[3] += bfhi(v.y);
    }
  };
  // half h consumes edges s+h, s+h+2, ... (2-deep unroll -> 4 rows in flight/wave)
  int j = s + half;
  for (; j + 2 < e; j += 4) {
    const int i0 = esorted[j];
    const int i1 = esorted[j + 2];
    addrow(a0, i0);
    addrow(a1, i1);
  }
  if (j < e) addrow(a0, esorted[j]);
  if (half == 0) addrow(a1, n);  // self loop once
  const float sc = nisq[n];
  float vals[V2];
#pragma unroll
  for (int i = 0; i < V2; ++i) {
    float t = a0[i] + a1[i];
    t += __shfl_xor(t, 32, 64);
    t *= sc;
    if (half == 0) {
      if (ADD_BIAS) t += bias[colbase + i];
      if (HAS_RES) t += resid[(size_t)n * DO + colbase + i];
    }
    vals[i] = t;
  }
  if (half == 0) {
    if constexpr (OUT_BF16) {
      unsigned short* tr = (unsigned short*)Tv + (size_t)n * DO + colbase;
      if constexpr (V2 == 8) {
        uint4 o;
        o.x = packbf(vals[0], vals[1]); o.y = packbf(vals[2], vals[3]);
        o.z = packbf(vals[4], vals[5]); o.w = packbf(vals[6], vals[7]);
        *reinterpret_cast<uint4*>(tr) = o;
      } else {
        uint2 o;
        o.x = packbf(vals[0], vals[1]); o.y = packbf(vals[2], vals[3]);
        *reinterpret_cast<uint2*>(tr) = o;
      }
    } else {
      float* tr = (float*)Tv + (size_t)n * DO + colbase;
      if constexpr (V2 == 8) {
        float4 o0 = {vals[0], vals[1], vals[2], vals[3]};
        float4 o1 = {vals[4], vals[5], vals[6], vals[7]};
        *reinterpret_cast<float4*>(tr) = o0;
        *reinterpret_cast<float4*>(tr + 4) = o1;
      } else {
        float4 o = {vals[0], vals[1], vals[2], vals[3]};
        *reinterpret_cast<float4*>(tr) = o;
      }
    }
  }
}

// ---------------- column sums for BN stats (f32 input, L4 only) ----------------
__global__ void stats_kernel(const float* __restrict__ T, float* __restrict__ colsum,
                             float* __restrict__ colsumsq, int n, int rowsPerBlock) {
  const int c = threadIdx.x;
  const int DO = blockDim.x;
  const int r0 = blockIdx.x * rowsPerBlock;
  int r1 = r0 + rowsPerBlock;
  if (r1 > n) r1 = n;
  float s = 0.f, q = 0.f;
  for (int r = r0; r < r1; ++r) {
    const float v = T[(size_t)r * DO + c];
    s += v;
    q += v * v;
  }
  atomicAdd(&colsum[c], s);
  atomicAdd(&colsumsq[c], q);
}

// ---------------- BN apply + LeakyReLU + nisq row-scale, bf16 -> bf16 (DO=256) ----------------
__global__ void bn_lrelu_nisq_kernel(const unsigned short* __restrict__ Tb,
                                     const float* __restrict__ colsum,
                                     const float* __restrict__ colsumsq,
                                     const float* __restrict__ g, const float* __restrict__ be,
                                     const float* __restrict__ nisq,
                                     unsigned short* __restrict__ outb,
                                     size_t total8, float invN) {
  const size_t idx = (size_t)blockIdx.x * 256 + threadIdx.x;
  if (idx >= total8) return;
  const unsigned c = ((unsigned)idx & 31u) * 8;
  const int row = (int)(idx >> 5);
  const float sc = nisq[row];
  uint4 v = *reinterpret_cast<const uint4*>(&Tb[idx * 8]);
  float z[8] = {bflo(v.x), bfhi(v.x), bflo(v.y), bfhi(v.y),
                bflo(v.z), bfhi(v.z), bflo(v.w), bfhi(v.w)};
  const float4 cs0 = *reinterpret_cast<const float4*>(&colsum[c]);
  const float4 cs1 = *reinterpret_cast<const float4*>(&colsum[c + 4]);
  const float4 cq0 = *reinterpret_cast<const float4*>(&colsumsq[c]);
  const float4 cq1 = *reinterpret_cast<const float4*>(&colsumsq[c + 4]);
  const float4 gv0 = *reinterpret_cast<const float4*>(&g[c]);
  const float4 gv1 = *reinterpret_cast<const float4*>(&g[c + 4]);
  const float4 bv0 = *reinterpret_cast<const float4*>(&be[c]);
  const float4 bv1 = *reinterpret_cast<const float4*>(&be[c + 4]);
  const float css[8] = {cs0.x, cs0.y, cs0.z, cs0.w, cs1.x, cs1.y, cs1.z, cs1.w};
  const float cqq[8] = {cq0.x, cq0.y, cq0.z, cq0.w, cq1.x, cq1.y, cq1.z, cq1.w};
  const float ggg[8] = {gv0.x, gv0.y, gv0.z, gv0.w, gv1.x, gv1.y, gv1.z, gv1.w};
  const float bbb[8] = {bv0.x, bv0.y, bv0.z, bv0.w, bv1.x, bv1.y, bv1.z, bv1.w};
#pragma unroll
  for (int k = 0; k < 8; ++k) {
    const float m = css[k] * invN;
    const float rs = rsqrtf(cqq[k] * invN - m * m + EPS_C);
    float zz = (z[k] - m) * rs * ggg[k] + bbb[k];
    zz = (zz >= 0.f) ? zz : SLOPE_C * zz;
    z[k] = zz * sc;
  }
  v.x = packbf(z[0], z[1]); v.y = packbf(z[2], z[3]);
  v.z = packbf(z[4], z[5]); v.w = packbf(z[6], z[7]);
  *reinterpret_cast<uint4*>(&outb[idx * 8]) = v;
}

// ---------------- final: BN apply + LayerNorm fused (DO=128) ----------------
__global__ __launch_bounds__(256) void bn_ln_kernel(
    const float* __restrict__ T, const float* __restrict__ colsum,
    const float* __restrict__ colsumsq, const float* __restrict__ g,
    const float* __restrict__ be, const float* __restrict__ lng,
    const float* __restrict__ lnb, float* __restrict__ out, float invN) {
  const int wave = threadIdx.x >> 6;
  const int lane = threadIdx.x & 63;
  const int n = blockIdx.x * 4 + wave;
  if (n >= N_NODES) return;
  const int c = lane * 2;
  const float2 t = *reinterpret_cast<const float2*>(&T[(size_t)n * 128 + c]);
  float z[2];
#pragma unroll
  for (int k = 0; k < 2; ++k) {
    const float m = colsum[c + k] * invN;
    const float v = colsumsq[c + k] * invN - m * m;
    const float tv = (k == 0) ? t.x : t.y;
    z[k] = (tv - m) * rsqrtf(v + EPS_C) * g[c + k] + be[c + k];
  }
  float s = z[0] + z[1];
  float q = z[0] * z[0] + z[1] * z[1];
  for (int o = 32; o > 0; o >>= 1) {
    s += __shfl_xor(s, o, 64);
    q += __shfl_xor(q, o, 64);
  }
  const float mean = s * (1.f / 128.f);
  const float var = q * (1.f / 128.f) - mean * mean;
  const float rs = rsqrtf(var + EPS_C);
  float2 o2;
  o2.x = (z[0] - mean) * rs * lng[c] + lnb[c];
  o2.y = (z[1] - mean) * rs * lng[c + 1] + lnb[c + 1];
  *reinterpret_cast<float2*>(&out[(size_t)n * 128 + c]) = o2;
}

extern "C" void kernel_launch(void* const* d_in, const int* in_sizes, int n_in,
                              void* d_out, int out_size, void* d_ws, size_t ws_size,
                              hipStream_t stream) {
  const float* x = (const float*)d_in[0];
  const int* ei = (const int*)d_in[1];
  const int* srcp = ei;
  const int* dstp = ei + N_EDGES;
  const float* W1 = (const float*)d_in[2];
  const float* b1 = (const float*)d_in[3];
  const float* g1 = (const float*)d_in[4];
  const float* be1 = (const float*)d_in[5];
  const float* W2 = (const float*)d_in[6];
  const float* b2 = (const float*)d_in[7];
  const float* g2 = (const float*)d_in[8];
  const float* be2 = (const float*)d_in[9];
  const float* W3 = (const float*)d_in[10];
  const float* b3 = (const float*)d_in[11];
  const float* g3 = (const float*)d_in[12];
  const float* be3 = (const float*)d_in[13];
  const float* W4 = (const float*)d_in[14];
  const float* b4 = (const float*)d_in[15];
  const float* g4 = (const float*)d_in[16];
  const float* be4 = (const float*)d_in[17];
  const float* lng = (const float*)d_in[18];
  const float* lnb = (const float*)d_in[19];
  float* out = (float*)d_out;

  char* ws = (char*)d_ws;
  size_t off_b = 0;
  auto alloc = [&](size_t bytes) -> void* {
    void* p = (void*)(ws + off_b);
    off_b += (bytes + 255) & ~(size_t)255;
    return p;
  };
  int* hist = (int*)alloc((size_t)N_NODES * 4);
  int* segoff = (int*)alloc((size_t)(N_NODES + 1) * 4);
  int* cursor = (int*)alloc((size_t)N_NODES * 4);
  float* nisq = (float*)alloc((size_t)N_NODES * 4);
  int* esorted = (int*)alloc((size_t)N_EDGES * 4);
  int* partial = (int*)alloc(64 * 4);
  int* partialoff = (int*)alloc(64 * 4);
  float* colsum = (float*)alloc(256 * 4);
  float* colsumsq = (float*)alloc(256 * 4);
  unsigned short* Wt1 = (unsigned short*)alloc((size_t)256 * 128 * 2);
  unsigned short* Wt2 = (unsigned short*)alloc((size_t)256 * 256 * 2);
  unsigned short* Wt3 = (unsigned short*)alloc((size_t)256 * 256 * 2);
  unsigned short* Wt4 = (unsigned short*)alloc((size_t)128 * 256 * 2);
  unsigned short* tblA = (unsigned short*)alloc((size_t)N_NODES * 256 * 2);
  unsigned short* tblB = (unsigned short*)alloc((size_t)N_NODES * 256 * 2);
  unsigned short* S = (unsigned short*)alloc((size_t)N_NODES * 256 * 2);
  unsigned short* Tb = (unsigned short*)alloc((size_t)N_NODES * 256 * 2);
  float* Tf = (float*)alloc((size_t)N_NODES * 128 * 4);

  const float invN = 1.0f / (float)N_NODES;
  const int egrid = (N_EDGES + 255) / 256;
  const int ngrid = (N_NODES + 255) / 256;
  const int aggrid = (N_NODES + 3) / 4;
  const int statgrid = (N_NODES + 127) / 128;
  const int nb = (N_NODES + 1023) / 1024;
  const dim3 mgrid256((N_NODES + 127) / 128, 4);
  const dim3 mgrid128((N_NODES + 127) / 128, 2);
  const unsigned bngrid = (unsigned)(((size_t)N_NODES * 32 + 255) / 256);

  // ---- degrees + dst-sorted edge list (counting sort) ----
  hipMemsetAsync(hist, 0, (size_t)N_NODES * 4, stream);
  hist_kernel<<<egrid, 256, 0, stream>>>(dstp, hist, N_EDGES);
  nisq_kernel<<<ngrid, 256, 0, stream>>>(hist, nisq, N_NODES);
  scan1_kernel<<<nb, 1024, 0, stream>>>(hist, segoff, partial, N_NODES);
  scan2_kernel<<<1, 64, 0, stream>>>(partial, partialoff, &segoff[N_NODES], nb);
  scan3_kernel<<<ngrid, 256, 0, stream>>>(segoff, cursor, partialoff, N_NODES);
  scatter_kernel<<<egrid, 256, 0, stream>>>(srcp, dstp, cursor, esorted, N_EDGES);

  // ---- weight transpose+cast ----
  wcast_kernel<<<(128 * 256 + 255) / 256, 256, 0, stream>>>(W1, Wt1, 128 * 256, 8, 255, 128);
  wcast_kernel<<<(256 * 256 + 255) / 256, 256, 0, stream>>>(W2, Wt2, 256 * 256, 8, 255, 256);
  wcast_kernel<<<(256 * 256 + 255) / 256, 256, 0, stream>>>(W3, Wt3, 256 * 256, 8, 255, 256);
  wcast_kernel<<<(256 * 128 + 255) / 256, 256, 0, stream>>>(W4, Wt4, 256 * 128, 7, 127, 256);

  // ---- Layer 1: table1 = x*nisq; S1 = A_hat-gather; T1 = S1 W1 + b1 (+stats); bn*nisq -> tblB
  scale_cast_kernel<<<(N_NODES * 32 + 255) / 256, 256, 0, stream>>>(x, nisq, tblA);
  aggregate3_kernel<128, false, false, true><<<aggrid, 256, 0, stream>>>(
      tblA, segoff, esorted, nisq, nullptr, nullptr, S);
  hipMemsetAsync(colsum, 0, 2048, stream);
  gemm_mfma_kernel<1><<<mgrid256, 256, 0, stream>>>(S, Wt1, b1, Tb, colsum, colsumsq,
                                                    N_NODES, 128, 256);
  bn_lrelu_nisq_kernel<<<bngrid, 256, 0, stream>>>(Tb, colsum, colsumsq, g1, be1, nisq,
                                                   tblB, (size_t)N_NODES * 32, invN);

  // ---- Layer 2 ----
  aggregate3_kernel<256, false, false, true><<<aggrid, 256, 0, stream>>>(
      tblB, segoff, esorted, nisq, nullptr, nullptr, S);
  hipMemsetAsync(colsum, 0, 2048, stream);
  gemm_mfma_kernel<1><<<mgrid256, 256, 0, stream>>>(S, Wt2, b2, Tb, colsum, colsumsq,
                                                    N_NODES, 256, 256);
  bn_lrelu_nisq_kernel<<<bngrid, 256, 0, stream>>>(Tb, colsum, colsumsq, g2, be2, nisq,
                                                   tblA, (size_t)N_NODES * 32, invN);

  // ---- Layer 3 ----
  aggregate3_kernel<256, false, false, true><<<aggrid, 256, 0, stream>>>(
      tblA, segoff, esorted, nisq, nullptr, nullptr, S);
  hipMemsetAsync(colsum, 0, 2048, stream);
  gemm_mfma_kernel<1><<<mgrid256, 256, 0, stream>>>(S, Wt3, b3, Tb, colsum, colsumsq,
                                                    N_NODES, 256, 256);
  bn_lrelu_nisq_kernel<<<bngrid, 256, 0, stream>>>(Tb, colsum, colsumsq, g3, be3, nisq,
                                                   tblB, (size_t)N_NODES * 32, invN);

  // ---- Layer 4: Y4 = tblB·W4 (nisq pre-folded); agg(+b4+resid) -> f32; stats; BN+LN ----
  gemm_mfma_kernel<0><<<mgrid128, 256, 0, stream>>>(tblB, Wt4, nullptr, S, nullptr, nullptr,
                                                    N_NODES, 256, 128);
  aggregate3_kernel<128, true, true, false><<<aggrid, 256, 0, stream>>>(
      S, segoff, esorted, nisq, b4, x, Tf);
  hipMemsetAsync(colsum, 0, 2048, stream);
  stats_kernel<<<statgrid, 128, 0, stream>>>(Tf, colsum, colsumsq, N_NODES, 128);
  bn_ln_kernel<<<aggrid, 256, 0, stream>>>(Tf, colsum, colsumsq, g4, be4, lng, lnb, out, invN);
}

// Round 6
// 531.605 us; speedup vs baseline: 2.1541x; 1.0455x over previous
//
#include <hip/hip_runtime.h>

#define N_NODES 50000
#define N_EDGES 800000
#define EPS_C 1e-5f
#define SLOPE_C 0.01f

typedef __attribute__((ext_vector_type(8))) short short8v;
typedef __attribute__((ext_vector_type(4))) float f32x4;

// ---------- bf16 helpers (RNE) ----------
__device__ __forceinline__ unsigned short f2bf(float f) {
  unsigned u = __float_as_uint(f);
  u += 0x7fffu + ((u >> 16) & 1u);
  return (unsigned short)(u >> 16);
}
__device__ __forceinline__ unsigned packbf(float a, float b) {
  return (unsigned)f2bf(a) | ((unsigned)f2bf(b) << 16);
}
__device__ __forceinline__ float bflo(unsigned u) { return __uint_as_float(u << 16); }
__device__ __forceinline__ float bfhi(unsigned u) { return __uint_as_float(u & 0xffff0000u); }

// ---------------- all-weights transpose + cast: Wt[m][k] = bf16(W[k][m]) ----------------
__global__ void wcast_all_kernel(const float* __restrict__ W1, const float* __restrict__ W2,
                                 const float* __restrict__ W3, const float* __restrict__ W4,
                                 unsigned short* __restrict__ Wt1, unsigned short* __restrict__ Wt2,
                                 unsigned short* __restrict__ Wt3, unsigned short* __restrict__ Wt4) {
  const int y = blockIdx.y;
  const int idx = blockIdx.x * 256 + threadIdx.x;
  const float* W;
  unsigned short* Wt;
  int K, mshift, mmask, total;
  switch (y) {
    case 0: W = W1; Wt = Wt1; K = 128; mshift = 8; mmask = 255; total = 32768; break;
    case 1: W = W2; Wt = Wt2; K = 256; mshift = 8; mmask = 255; total = 65536; break;
    case 2: W = W3; Wt = Wt3; K = 256; mshift = 8; mmask = 255; total = 65536; break;
    default: W = W4; Wt = Wt4; K = 256; mshift = 7; mmask = 127; total = 32768; break;
  }
  if (idx >= total) return;
  const int k = idx >> mshift;
  const int m = idx & mmask;
  Wt[(size_t)m * K + k] = f2bf(W[idx]);
}

// ---------------- MFMA GEMM ----------------
// MODE 0: Yb = bf16(A·Wt^T)                       (L4: nisq already folded into A's table)
// MODE 1: Yb = bf16(A·Wt^T + bias), fused col stats (L1/L2/L3)
template <int MODE>
__global__ __launch_bounds__(256) void gemm_mfma_kernel(
    const unsigned short* __restrict__ A, const unsigned short* __restrict__ Wt,
    const float* __restrict__ bias, unsigned short* __restrict__ Yb,
    float* __restrict__ colsum, float* __restrict__ colsumsq,
    int Nrows, int K, int M) {
  __shared__ __align__(16) unsigned short As[128][72];
  __shared__ __align__(16) unsigned short Bs[64][72];
  __shared__ float sred[2][64][8];
  const int tid = threadIdx.x;
  const int lane = tid & 63;
  const int wave = tid >> 6;
  const int wr = wave >> 1, wc = wave & 1;
  const int row0 = blockIdx.x * 128;
  const int col0 = blockIdx.y * 64;
  const int l15 = lane & 15;
  const int lhi = lane >> 4;
  f32x4 acc[4][2];
#pragma unroll
  for (int i = 0; i < 4; ++i)
#pragma unroll
    for (int j = 0; j < 2; ++j) acc[i][j] = (f32x4){0.f, 0.f, 0.f, 0.f};

  for (int k0 = 0; k0 < K; k0 += 64) {
#pragma unroll
    for (int c = 0; c < 4; ++c) {
      const int id = tid + c * 256;
      const int r = id >> 3;
      const int ck = (id & 7) * 8;
      short8v v = {};
      const int grow = row0 + r;
      if (grow < Nrows)
        v = *reinterpret_cast<const short8v*>(&A[(size_t)grow * K + k0 + ck]);
      *reinterpret_cast<short8v*>(&As[r][ck]) = v;
    }
#pragma unroll
    for (int c = 0; c < 2; ++c) {
      const int id = tid + c * 256;
      const int r = id >> 3;
      const int ck = (id & 7) * 8;
      const short8v v =
          *reinterpret_cast<const short8v*>(&Wt[(size_t)(col0 + r) * K + k0 + ck]);
      *reinterpret_cast<short8v*>(&Bs[r][ck]) = v;
    }
    __syncthreads();
    short8v bfr[2][2];
#pragma unroll
    for (int nr = 0; nr < 2; ++nr)
#pragma unroll
      for (int h = 0; h < 2; ++h)
        bfr[nr][h] = *reinterpret_cast<const short8v*>(
            &Bs[wc * 32 + nr * 16 + l15][h * 32 + lhi * 8]);
#pragma unroll
    for (int mr = 0; mr < 4; ++mr) {
#pragma unroll
      for (int h = 0; h < 2; ++h) {
        const short8v af = *reinterpret_cast<const short8v*>(
            &As[wr * 64 + mr * 16 + l15][h * 32 + lhi * 8]);
#pragma unroll
        for (int nr = 0; nr < 2; ++nr)
          acc[mr][nr] = __builtin_amdgcn_mfma_f32_16x16x32_bf16(
              af, bfr[nr][h], acc[mr][nr], 0, 0, 0);
      }
    }
    __syncthreads();
  }
  // epilogue
  float bcol[2] = {0.f, 0.f};
  if constexpr (MODE == 1) {
#pragma unroll
    for (int nr = 0; nr < 2; ++nr) bcol[nr] = bias[col0 + wc * 32 + nr * 16 + l15];
  }
  float s_c[2] = {0.f, 0.f}, q_c[2] = {0.f, 0.f};
#pragma unroll
  for (int mr = 0; mr < 4; ++mr) {
#pragma unroll
    for (int r = 0; r < 4; ++r) {
      const int grow = row0 + wr * 64 + mr * 16 + lhi * 4 + r;
      const bool ok = (grow < Nrows);
#pragma unroll
      for (int nr = 0; nr < 2; ++nr) {
        const int gcol = col0 + wc * 32 + nr * 16 + l15;
        float v = acc[mr][nr][r] + bcol[nr];
        if (ok) {
          Yb[(size_t)grow * M + gcol] = f2bf(v);
          if constexpr (MODE == 1) {
            s_c[nr] += v;
            q_c[nr] += v * v;
          }
        }
      }
    }
  }
  if constexpr (MODE == 1) {
    const int contrib = wr * 4 + lhi;
#pragma unroll
    for (int nr = 0; nr < 2; ++nr) {
      const int cl = wc * 32 + nr * 16 + l15;
      sred[0][cl][contrib] = s_c[nr];
      sred[1][cl][contrib] = q_c[nr];
    }
    __syncthreads();
    if (tid < 128) {
      const int which = tid >> 6;  // 0: sum, 1: sumsq
      const int cl = tid & 63;
      float acc8 = 0.f;
#pragma unroll
      for (int k = 0; k < 8; ++k) acc8 += sred[which][cl][k];
      float* dstp = which ? colsumsq : colsum;
      atomicAdd(&dstp[col0 + cl], acc8);
    }
  }
}

// ---------------- degree histogram ----------------
__global__ void hist_kernel(const int* __restrict__ dst, int* __restrict__ hist, int E) {
  const int e = blockIdx.x * 256 + threadIdx.x;
  if (e < E) atomicAdd(&hist[dst[e]], 1);
}

// ---------------- two-level exclusive scan (scan1 also emits nisq) ----------------
__global__ __launch_bounds__(1024) void scan1_kernel(
    const int* __restrict__ hist, int* __restrict__ off, int* __restrict__ partial,
    float* __restrict__ nisq, int n) {
  __shared__ int tmp[1024];
  const int tid = threadIdx.x;
  const int i = blockIdx.x * 1024 + tid;
  const int v = (i < n) ? hist[i] : 0;
  tmp[tid] = v;
  __syncthreads();
  int x = v;
  for (int o = 1; o < 1024; o <<= 1) {
    const int y = (tid >= o) ? tmp[tid - o] : 0;
    __syncthreads();
    x += y;
    tmp[tid] = x;
    __syncthreads();
  }
  if (i < n) {
    off[i] = x - v;
    nisq[i] = rsqrtf((float)v + 1.0f);
  }
  if (tid == 1023) partial[blockIdx.x] = x;
}

__global__ __launch_bounds__(64) void scan2_kernel(
    const int* __restrict__ partial, int* __restrict__ partialoff,
    int* __restrict__ offN, int nb) {
  const int tid = threadIdx.x;
  const int v = (tid < nb) ? partial[tid] : 0;
  int x = v;
  for (int o = 1; o < 64; o <<= 1) {
    const int y = __shfl_up(x, o, 64);
    if (tid >= o) x += y;
  }
  if (tid < nb) partialoff[tid] = x - v;
  if (tid == 63) *offN = x;
}

__global__ void scan3_kernel(int* __restrict__ off, int* __restrict__ cursor,
                             const int* __restrict__ partialoff, int n) {
  const int i = blockIdx.x * 256 + threadIdx.x;
  if (i < n) {
    const int o = off[i] + partialoff[i >> 10];
    off[i] = o;
    cursor[i] = o;
  }
}

// ---------------- scatter edges into dst-sorted order ----------------
__global__ void scatter_kernel(const int* __restrict__ src, const int* __restrict__ dst,
                               int* __restrict__ cursor, int* __restrict__ esorted, int E) {
  const int e = blockIdx.x * 256 + threadIdx.x;
  if (e < E) {
    const int p = atomicAdd(&cursor[dst[e]], 1);
    esorted[p] = src[e];
  }
}

// ---------------- scale+cast: xs = bf16(x * nisq[row]), DI=128 ----------------
__global__ void scale_cast_kernel(const float* __restrict__ x,
                                  const float* __restrict__ nisq,
                                  unsigned short* __restrict__ xs) {
  const int idx = blockIdx.x * 256 + threadIdx.x;
  if (idx >= N_NODES * 32) return;
  const int row = idx >> 5;
  const int c = (idx & 31) * 4;
  const float s = nisq[row];
  const float4 v = *reinterpret_cast<const float4*>(&x[(size_t)row * 128 + c]);
  ushort4 o;
  o.x = f2bf(v.x * s); o.y = f2bf(v.y * s);
  o.z = f2bf(v.z * s); o.w = f2bf(v.w * s);
  *reinterpret_cast<ushort4*>(&xs[(size_t)row * 128 + c]) = o;
}

// ---------------- pure gather aggregation (half-wave, 16B/lane, 4-batched loads) ----------------
template <int DO, bool ADD_BIAS, bool HAS_RES, bool OUT_BF16>
__global__ __launch_bounds__(256) void aggregate4_kernel(
    const unsigned short* __restrict__ Y, const int* __restrict__ segoff,
    const int* __restrict__ esorted, const float* __restrict__ nisq,
    const float* __restrict__ bias, const float* __restrict__ resid,
    void* __restrict__ Tv) {
  constexpr int V2 = DO / 32;  // bf16 elems per lane per row (128: 4, 256: 8)
  const int wave = threadIdx.x >> 6;
  const int lane = threadIdx.x & 63;
  const int half = lane >> 5;
  const int l31 = lane & 31;
  const int n = blockIdx.x * 4 + wave;
  if (n >= N_NODES) return;
  const int colbase = l31 * V2;
  const unsigned short* Yc = Y + colbase;
  float a0[V2], a1[V2];
#pragma unroll
  for (int i = 0; i < V2; ++i) { a0[i] = 0.f; a1[i] = 0.f; }
  const int s = segoff[n];
  const int e = segoff[n + 1];

  if constexpr (V2 == 8) {
    auto acc8 = [&](float* a, const uint4 v) {
      a[0] += bflo(v.x); a[1] += bfhi(v.x);
      a[2] += bflo(v.y); a[3] += bfhi(v.y);
      a[4] += bflo(v.z); a[5] += bfhi(v.z);
      a[6] += bflo(v.w); a[7] += bfhi(v.w);
    };
    int j = s + half;
    for (; j + 6 < e; j += 8) {
      const int i0 = esorted[j];
      const int i1 = esorted[j + 2];
      const int i2 = esorted[j + 4];
      const int i3 = esorted[j + 6];
      const uint4 v0 = *reinterpret_cast<const uint4*>(Yc + (size_t)i0 * DO);
      const uint4 v1 = *reinterpret_cast<const uint4*>(Yc + (size_t)i1 * DO);
      const uint4 v2 = *reinterpret_cast<const uint4*>(Yc + (size_t)i2 * DO);
      const uint4 v3 = *reinterpret_cast<const uint4*>(Yc + (size_t)i3 * DO);
      acc8(a0, v0); acc8(a1, v1); acc8(a0, v2); acc8(a1, v3);
    }
    for (; j < e; j += 2)
      acc8(a0, *reinterpret_cast<const uint4*>(Yc + (size_t)esorted[j] * DO));
    if (half == 0) acc8(a1, *reinterpret_cast<const uint4*>(Yc + (size_t)n * DO));
  } else {
    auto acc4 = [&](float* a, const uint2 v) {
      a[0] += bflo(v.x); a[1] += bfhi(v.x);
      a[2] += bflo(v.y); a[3] += bfhi(v.y);
    };
    int j = s + half;
    for (; j + 6 < e; j += 8) {
      const int i0 = esorted[j];
      const int i1 = esorted[j + 2];
      const int i2 = esorted[j + 4];
      const int i3 = esorted[j + 6];
      const uint2 v0 = *reinterpret_cast<const uint2*>(Yc + (size_t)i0 * DO);
      const uint2 v1 = *reinterpret_cast<const uint2*>(Yc + (size_t)i1 * DO);
      const uint2 v2 = *reinterpret_cast<const uint2*>(Yc + (size_t)i2 * DO);
      const uint2 v3 = *reinterpret_cast<const uint2*>(Yc + (size_t)i3 * DO);
      acc4(a0, v0); acc4(a1, v1); acc4(a0, v2); acc4(a1, v3);
    }
    for (; j < e; j += 2)
      acc4(a0, *reinterpret_cast<const uint2*>(Yc + (size_t)esorted[j] * DO));
    if (half == 0) acc4(a1, *reinterpret_cast<const uint2*>(Yc + (size_t)n * DO));
  }

  const float sc = nisq[n];
  float vals[V2];
#pragma unroll
  for (int i = 0; i < V2; ++i) {
    float t = a0[i] + a1[i];
    t += __shfl_xor(t, 32, 64);
    t *= sc;
    if (half == 0) {
      if (ADD_BIAS) t += bias[colbase + i];
      if (HAS_RES) t += resid[(size_t)n * DO + colbase + i];
    }
    vals[i] = t;
  }
  if (half == 0) {
    if constexpr (OUT_BF16) {
      unsigned short* tr = (unsigned short*)Tv + (size_t)n * DO + colbase;
      if constexpr (V2 == 8) {
        uint4 o;
        o.x = packbf(vals[0], vals[1]); o.y = packbf(vals[2], vals[3]);
        o.z = packbf(vals[4], vals[5]); o.w = packbf(vals[6], vals[7]);
        *reinterpret_cast<uint4*>(tr) = o;
      } else {
        uint2 o;
        o.x = packbf(vals[0], vals[1]); o.y = packbf(vals[2], vals[3]);
        *reinterpret_cast<uint2*>(tr) = o;
      }
    } else {
      float* tr = (float*)Tv + (size_t)n * DO + colbase;
      if constexpr (V2 == 8) {
        float4 o0 = {vals[0], vals[1], vals[2], vals[3]};
        float4 o1 = {vals[4], vals[5], vals[6], vals[7]};
        *reinterpret_cast<float4*>(tr) = o0;
        *reinterpret_cast<float4*>(tr + 4) = o1;
      } else {
        float4 o = {vals[0], vals[1], vals[2], vals[3]};
        *reinterpret_cast<float4*>(tr) = o;
      }
    }
  }
}

// ---------------- column sums for BN stats (f32 input, L4 only) ----------------
__global__ void stats_kernel(const float* __restrict__ T, float* __restrict__ colsum,
                             float* __restrict__ colsumsq, int n, int rowsPerBlock) {
  const int c = threadIdx.x;
  const int DO = blockDim.x;
  const int r0 = blockIdx.x * rowsPerBlock;
  int r1 = r0 + rowsPerBlock;
  if (r1 > n) r1 = n;
  float s = 0.f, q = 0.f;
  for (int r = r0; r < r1; ++r) {
    const float v = T[(size_t)r * DO + c];
    s += v;
    q += v * v;
  }
  atomicAdd(&colsum[c], s);
  atomicAdd(&colsumsq[c], q);
}

// ---------------- BN apply + LeakyReLU + nisq row-scale, bf16 -> bf16 (DO=256) ----------------
__global__ void bn_lrelu_nisq_kernel(const unsigned short* __restrict__ Tb,
                                     const float* __restrict__ colsum,
                                     const float* __restrict__ colsumsq,
                                     const float* __restrict__ g, const float* __restrict__ be,
                                     const float* __restrict__ nisq,
                                     unsigned short* __restrict__ outb,
                                     size_t total8, float invN) {
  const size_t idx = (size_t)blockIdx.x * 256 + threadIdx.x;
  if (idx >= total8) return;
  const unsigned c = ((unsigned)idx & 31u) * 8;
  const int row = (int)(idx >> 5);
  const float sc = nisq[row];
  uint4 v = *reinterpret_cast<const uint4*>(&Tb[idx * 8]);
  float z[8] = {bflo(v.x), bfhi(v.x), bflo(v.y), bfhi(v.y),
                bflo(v.z), bfhi(v.z), bflo(v.w), bfhi(v.w)};
  const float4 cs0 = *reinterpret_cast<const float4*>(&colsum[c]);
  const float4 cs1 = *reinterpret_cast<const float4*>(&colsum[c + 4]);
  const float4 cq0 = *reinterpret_cast<const float4*>(&colsumsq[c]);
  const float4 cq1 = *reinterpret_cast<const float4*>(&colsumsq[c + 4]);
  const float4 gv0 = *reinterpret_cast<const float4*>(&g[c]);
  const float4 gv1 = *reinterpret_cast<const float4*>(&g[c + 4]);
  const float4 bv0 = *reinterpret_cast<const float4*>(&be[c]);
  const float4 bv1 = *reinterpret_cast<const float4*>(&be[c + 4]);
  const float css[8] = {cs0.x, cs0.y, cs0.z, cs0.w, cs1.x, cs1.y, cs1.z, cs1.w};
  const float cqq[8] = {cq0.x, cq0.y, cq0.z, cq0.w, cq1.x, cq1.y, cq1.z, cq1.w};
  const float ggg[8] = {gv0.x, gv0.y, gv0.z, gv0.w, gv1.x, gv1.y, gv1.z, gv1.w};
  const float bbb[8] = {bv0.x, bv0.y, bv0.z, bv0.w, bv1.x, bv1.y, bv1.z, bv1.w};
#pragma unroll
  for (int k = 0; k < 8; ++k) {
    const float m = css[k] * invN;
    const float rs = rsqrtf(cqq[k] * invN - m * m + EPS_C);
    float zz = (z[k] - m) * rs * ggg[k] + bbb[k];
    zz = (zz >= 0.f) ? zz : SLOPE_C * zz;
    z[k] = zz * sc;
  }
  v.x = packbf(z[0], z[1]); v.y = packbf(z[2], z[3]);
  v.z = packbf(z[4], z[5]); v.w = packbf(z[6], z[7]);
  *reinterpret_cast<uint4*>(&outb[idx * 8]) = v;
}

// ---------------- final: BN apply + LayerNorm fused (DO=128) ----------------
__global__ __launch_bounds__(256) void bn_ln_kernel(
    const float* __restrict__ T, const float* __restrict__ colsum,
    const float* __restrict__ colsumsq, const float* __restrict__ g,
    const float* __restrict__ be, const float* __restrict__ lng,
    const float* __restrict__ lnb, float* __restrict__ out, float invN) {
  const int wave = threadIdx.x >> 6;
  const int lane = threadIdx.x & 63;
  const int n = blockIdx.x * 4 + wave;
  if (n >= N_NODES) return;
  const int c = lane * 2;
  const float2 t = *reinterpret_cast<const float2*>(&T[(size_t)n * 128 + c]);
  float z[2];
#pragma unroll
  for (int k = 0; k < 2; ++k) {
    const float m = colsum[c + k] * invN;
    const float v = colsumsq[c + k] * invN - m * m;
    const float tv = (k == 0) ? t.x : t.y;
    z[k] = (tv - m) * rsqrtf(v + EPS_C) * g[c + k] + be[c + k];
  }
  float s = z[0] + z[1];
  float q = z[0] * z[0] + z[1] * z[1];
  for (int o = 32; o > 0; o >>= 1) {
    s += __shfl_xor(s, o, 64);
    q += __shfl_xor(q, o, 64);
  }
  const float mean = s * (1.f / 128.f);
  const float var = q * (1.f / 128.f) - mean * mean;
  const float rs = rsqrtf(var + EPS_C);
  float2 o2;
  o2.x = (z[0] - mean) * rs * lng[c] + lnb[c];
  o2.y = (z[1] - mean) * rs * lng[c + 1] + lnb[c + 1];
  *reinterpret_cast<float2*>(&out[(size_t)n * 128 + c]) = o2;
}

extern "C" void kernel_launch(void* const* d_in, const int* in_sizes, int n_in,
                              void* d_out, int out_size, void* d_ws, size_t ws_size,
                              hipStream_t stream) {
  const float* x = (const float*)d_in[0];
  const int* ei = (const int*)d_in[1];
  const int* srcp = ei;
  const int* dstp = ei + N_EDGES;
  const float* W1 = (const float*)d_in[2];
  const float* b1 = (const float*)d_in[3];
  const float* g1 = (const float*)d_in[4];
  const float* be1 = (const float*)d_in[5];
  const float* W2 = (const float*)d_in[6];
  const float* b2 = (const float*)d_in[7];
  const float* g2 = (const float*)d_in[8];
  const float* be2 = (const float*)d_in[9];
  const float* W3 = (const float*)d_in[10];
  const float* b3 = (const float*)d_in[11];
  const float* g3 = (const float*)d_in[12];
  const float* be3 = (const float*)d_in[13];
  const float* W4 = (const float*)d_in[14];
  const float* b4 = (const float*)d_in[15];
  const float* g4 = (const float*)d_in[16];
  const float* be4 = (const float*)d_in[17];
  const float* lng = (const float*)d_in[18];
  const float* lnb = (const float*)d_in[19];
  float* out = (float*)d_out;

  char* ws = (char*)d_ws;
  size_t off_b = 0;
  auto alloc = [&](size_t bytes) -> void* {
    void* p = (void*)(ws + off_b);
    off_b += (bytes + 255) & ~(size_t)255;
    return p;
  };
  // ---- zero-region (one memset): hist + per-layer stats buffers ----
  int* hist = (int*)alloc((size_t)N_NODES * 4);
  float* cs1 = (float*)alloc(256 * 4);
  float* cq1 = (float*)alloc(256 * 4);
  float* cs2 = (float*)alloc(256 * 4);
  float* cq2 = (float*)alloc(256 * 4);
  float* cs3 = (float*)alloc(256 * 4);
  float* cq3 = (float*)alloc(256 * 4);
  float* cs4 = (float*)alloc(256 * 4);
  float* cq4 = (float*)alloc(256 * 4);
  const size_t zero_bytes = off_b;
  // ---- rest ----
  int* segoff = (int*)alloc((size_t)(N_NODES + 1) * 4);
  int* cursor = (int*)alloc((size_t)N_NODES * 4);
  float* nisq = (float*)alloc((size_t)N_NODES * 4);
  int* esorted = (int*)alloc((size_t)N_EDGES * 4);
  int* partial = (int*)alloc(64 * 4);
  int* partialoff = (int*)alloc(64 * 4);
  unsigned short* Wt1 = (unsigned short*)alloc((size_t)256 * 128 * 2);
  unsigned short* Wt2 = (unsigned short*)alloc((size_t)256 * 256 * 2);
  unsigned short* Wt3 = (unsigned short*)alloc((size_t)256 * 256 * 2);
  unsigned short* Wt4 = (unsigned short*)alloc((size_t)128 * 256 * 2);
  unsigned short* tblA = (unsigned short*)alloc((size_t)N_NODES * 256 * 2);
  unsigned short* tblB = (unsigned short*)alloc((size_t)N_NODES * 256 * 2);
  unsigned short* S = (unsigned short*)alloc((size_t)N_NODES * 256 * 2);
  unsigned short* Tb = (unsigned short*)alloc((size_t)N_NODES * 256 * 2);
  float* Tf = (float*)alloc((size_t)N_NODES * 128 * 4);

  const float invN = 1.0f / (float)N_NODES;
  const int egrid = (N_EDGES + 255) / 256;
  const int ngrid = (N_NODES + 255) / 256;
  const int aggrid = (N_NODES + 3) / 4;
  const int statgrid = (N_NODES + 127) / 128;
  const int nb = (N_NODES + 1023) / 1024;
  const dim3 mgrid256((N_NODES + 127) / 128, 4);
  const dim3 mgrid128((N_NODES + 127) / 128, 2);
  const unsigned bngrid = (unsigned)(((size_t)N_NODES * 32 + 255) / 256);

  // ---- zero hist + all stats buffers in ONE memset ----
  hipMemsetAsync(hist, 0, zero_bytes, stream);

  // ---- degrees + nisq + dst-sorted edge list (counting sort) ----
  hist_kernel<<<egrid, 256, 0, stream>>>(dstp, hist, N_EDGES);
  scan1_kernel<<<nb, 1024, 0, stream>>>(hist, segoff, partial, nisq, N_NODES);
  scan2_kernel<<<1, 64, 0, stream>>>(partial, partialoff, &segoff[N_NODES], nb);
  scan3_kernel<<<ngrid, 256, 0, stream>>>(segoff, cursor, partialoff, N_NODES);
  scatter_kernel<<<egrid, 256, 0, stream>>>(srcp, dstp, cursor, esorted, N_EDGES);

  // ---- weights transpose+cast (one dispatch) ----
  wcast_all_kernel<<<dim3(256, 4), 256, 0, stream>>>(W1, W2, W3, W4, Wt1, Wt2, Wt3, Wt4);

  // ---- Layer 1: tblA = x*nisq; S = A_hat-gather; Tb = S W1 + b1 (+stats); bn*nisq -> tblB
  scale_cast_kernel<<<(N_NODES * 32 + 255) / 256, 256, 0, stream>>>(x, nisq, tblA);
  aggregate4_kernel<128, false, false, true><<<aggrid, 256, 0, stream>>>(
      tblA, segoff, esorted, nisq, nullptr, nullptr, S);
  gemm_mfma_kernel<1><<<mgrid256, 256, 0, stream>>>(S, Wt1, b1, Tb, cs1, cq1,
                                                    N_NODES, 128, 256);
  bn_lrelu_nisq_kernel<<<bngrid, 256, 0, stream>>>(Tb, cs1, cq1, g1, be1, nisq,
                                                   tblB, (size_t)N_NODES * 32, invN);

  // ---- Layer 2 ----
  aggregate4_kernel<256, false, false, true><<<aggrid, 256, 0, stream>>>(
      tblB, segoff, esorted, nisq, nullptr, nullptr, S);
  gemm_mfma_kernel<1><<<mgrid256, 256, 0, stream>>>(S, Wt2, b2, Tb, cs2, cq2,
                                                    N_NODES, 256, 256);
  bn_lrelu_nisq_kernel<<<bngrid, 256, 0, stream>>>(Tb, cs2, cq2, g2, be2, nisq,
                                                   tblA, (size_t)N_NODES * 32, invN);

  // ---- Layer 3 ----
  aggregate4_kernel<256, false, false, true><<<aggrid, 256, 0, stream>>>(
      tblA, segoff, esorted, nisq, nullptr, nullptr, S);
  gemm_mfma_kernel<1><<<mgrid256, 256, 0, stream>>>(S, Wt3, b3, Tb, cs3, cq3,
                                                    N_NODES, 256, 256);
  bn_lrelu_nisq_kernel<<<bngrid, 256, 0, stream>>>(Tb, cs3, cq3, g3, be3, nisq,
                                                   tblB, (size_t)N_NODES * 32, invN);

  // ---- Layer 4: S = tblB·W4 (nisq pre-folded); agg(+b4+resid) -> f32; stats; BN+LN ----
  gemm_mfma_kernel<0><<<mgrid128, 256, 0, stream>>>(tblB, Wt4, nullptr, S, nullptr, nullptr,
                                                    N_NODES, 256, 128);
  aggregate4_kernel<128, true, true, false><<<aggrid, 256, 0, stream>>>(
      S, segoff, esorted, nisq, b4, x, Tf);
  stats_kernel<<<statgrid, 128, 0, stream>>>(Tf, cs4, cq4, N_NODES, 128);
  bn_ln_kernel<<<aggrid, 256, 0, stream>>>(Tf, cs4, cq4, g4, be4, lng, lnb, out, invN);
}

// Round 7
// 504.224 us; speedup vs baseline: 2.2710x; 1.0543x over previous
//
#include <hip/hip_runtime.h>

#define N_NODES 50000
#define NPAD 50176            // 392 * 128
#define N_EDGES 800000
#define EPS_C 1e-5f
#define SLOPE_C 0.01f

typedef __attribute__((ext_vector_type(8))) short short8v;
typedef __attribute__((ext_vector_type(4))) float f32x4;

// ---------- bf16 helpers (RNE) ----------
__device__ __forceinline__ unsigned short f2bf(float f) {
  unsigned u = __float_as_uint(f);
  u += 0x7fffu + ((u >> 16) & 1u);
  return (unsigned short)(u >> 16);
}
__device__ __forceinline__ unsigned packbf(float a, float b) {
  return (unsigned)f2bf(a) | ((unsigned)f2bf(b) << 16);
}
__device__ __forceinline__ float bflo(unsigned u) { return __uint_as_float(u << 16); }
__device__ __forceinline__ float bfhi(unsigned u) { return __uint_as_float(u & 0xffff0000u); }

// ---------- async global->LDS, 16 B per lane ----------
__device__ __forceinline__ void gload16(const unsigned short* g, unsigned short* l) {
  __builtin_amdgcn_global_load_lds(
      (const __attribute__((address_space(1))) unsigned int*)g,
      (__attribute__((address_space(3))) unsigned int*)l, 16, 0, 0);
}

// ---------------- all-weights transpose + cast: Wt[m][k] = bf16(W[k][m]) ----------------
__global__ void wcast_all_kernel(const float* __restrict__ W1, const float* __restrict__ W2,
                                 const float* __restrict__ W3, const float* __restrict__ W4,
                                 unsigned short* __restrict__ Wt1, unsigned short* __restrict__ Wt2,
                                 unsigned short* __restrict__ Wt3, unsigned short* __restrict__ Wt4) {
  const int y = blockIdx.y;
  const int idx = blockIdx.x * 256 + threadIdx.x;
  const float* W;
  unsigned short* Wt;
  int K, mshift, mmask, total;
  switch (y) {
    case 0: W = W1; Wt = Wt1; K = 128; mshift = 8; mmask = 255; total = 32768; break;
    case 1: W = W2; Wt = Wt2; K = 256; mshift = 8; mmask = 255; total = 65536; break;
    case 2: W = W3; Wt = Wt3; K = 256; mshift = 8; mmask = 255; total = 65536; break;
    default: W = W4; Wt = Wt4; K = 256; mshift = 7; mmask = 127; total = 32768; break;
  }
  if (idx >= total) return;
  const int k = idx >> mshift;
  const int m = idx & mmask;
  Wt[(size_t)m * K + k] = f2bf(W[idx]);
}

// ---------------- MFMA GEMM v2: persistent swizzled B panel + global_load_lds A ----------------
// A: NPAD x KC bf16 (pad rows zero). Wt: M x KC bf16.
// MODE 0: Yb = bf16(A·Wt^T)          MODE 1: Yb = bf16(A·Wt^T + bias) + fused col stats
template <int MODE, int KC>
__global__ __launch_bounds__(256) void gemm2_kernel(
    const unsigned short* __restrict__ A, const unsigned short* __restrict__ Wt,
    const float* __restrict__ bias, unsigned short* __restrict__ Yb,
    float* __restrict__ colsum, float* __restrict__ colsumsq, int M) {
  __shared__ __align__(16) unsigned short Bs[64][KC];   // swizzled
  __shared__ __align__(16) unsigned short As[128][64];  // swizzled (linear dest, src-swizzled)
  __shared__ float sred[2][64][2];
  const int tid = threadIdx.x;
  const int lane = tid & 63;
  const int wave = tid >> 6;
  const int wr = wave >> 1, wc = wave & 1;
  const int row0 = blockIdx.x * 128;
  const int col0 = blockIdx.y * 64;
  const int l15 = lane & 15;
  const int lhi = lane >> 4;

  // ---- stage full B panel once (64 cols x KC), XOR-swizzled chunks ----
  constexpr int CPR = KC / 8;           // 16B chunks per B row (16 or 32)
  constexpr int BITER = 64 * CPR / 256; // staging iterations (4 or 8)
#pragma unroll
  for (int c = 0; c < BITER; ++c) {
    const int ch = c * 256 + tid;
    const int rb = ch / CPR;
    const int cb = ch % CPR;
    const short8v v =
        *reinterpret_cast<const short8v*>(&Wt[(size_t)(col0 + rb) * KC + cb * 8]);
    *reinterpret_cast<short8v*>(&Bs[rb][(cb ^ (rb & 7)) * 8]) = v;
  }

  f32x4 acc[4][2];
#pragma unroll
  for (int i = 0; i < 4; ++i)
#pragma unroll
    for (int j = 0; j < 2; ++j) acc[i][j] = (f32x4){0.f, 0.f, 0.f, 0.f};

  for (int k0 = 0; k0 < KC; k0 += 64) {
    __syncthreads();  // previous step's readers done (also orders B writes on iter 0)
    // ---- issue A tile staging: 1024 x 16B chunks, LDS linear, global src pre-swizzled ----
#pragma unroll
    for (int c = 0; c < 4; ++c) {
      const int chunk = (c * 4 + wave) * 64 + lane;
      const int r = chunk >> 3;
      const int cksrc = (chunk & 7) ^ (r & 7);
      gload16(&A[(size_t)(row0 + r) * KC + k0 + cksrc * 8], &As[0][0] + chunk * 8);
    }
    __syncthreads();  // drains vmcnt: A tile resident
    // ---- MFMA ----
    short8v bfr[2][2];
#pragma unroll
    for (int nr = 0; nr < 2; ++nr)
#pragma unroll
      for (int h = 0; h < 2; ++h) {
        const int rowb = wc * 32 + nr * 16 + l15;
        const int chb = (k0 >> 3) + h * 4 + lhi;
        bfr[nr][h] = *reinterpret_cast<const short8v*>(&Bs[rowb][(chb ^ (rowb & 7)) * 8]);
      }
#pragma unroll
    for (int mr = 0; mr < 4; ++mr) {
#pragma unroll
      for (int h = 0; h < 2; ++h) {
        const int rowa = wr * 64 + mr * 16 + l15;
        const int cha = (h * 4 + lhi) ^ (rowa & 7);
        const short8v af = *reinterpret_cast<const short8v*>(&As[rowa][cha * 8]);
#pragma unroll
        for (int nr = 0; nr < 2; ++nr)
          acc[mr][nr] = __builtin_amdgcn_mfma_f32_16x16x32_bf16(
              af, bfr[nr][h], acc[mr][nr], 0, 0, 0);
      }
    }
  }
  // ---- epilogue: unguarded stores (pads exist+harmless); stats guarded to real rows ----
  float bcol[2] = {0.f, 0.f};
  if constexpr (MODE == 1) {
#pragma unroll
    for (int nr = 0; nr < 2; ++nr) bcol[nr] = bias[col0 + wc * 32 + nr * 16 + l15];
  }
  float s_c[2] = {0.f, 0.f}, q_c[2] = {0.f, 0.f};
#pragma unroll
  for (int mr = 0; mr < 4; ++mr) {
#pragma unroll
    for (int r = 0; r < 4; ++r) {
      const int grow = row0 + wr * 64 + mr * 16 + lhi * 4 + r;
#pragma unroll
      for (int nr = 0; nr < 2; ++nr) {
        const int gcol = col0 + wc * 32 + nr * 16 + l15;
        const float v = acc[mr][nr][r] + bcol[nr];
        Yb[(size_t)grow * M + gcol] = f2bf(v);
        if constexpr (MODE == 1) {
          if (grow < N_NODES) {
            s_c[nr] += v;
            q_c[nr] += v * v;
          }
        }
      }
    }
  }
  if constexpr (MODE == 1) {
#pragma unroll
    for (int nr = 0; nr < 2; ++nr) {
      float s = s_c[nr], q = q_c[nr];
      s += __shfl_xor(s, 16, 64); q += __shfl_xor(q, 16, 64);
      s += __shfl_xor(s, 32, 64); q += __shfl_xor(q, 32, 64);
      if (lhi == 0) {
        const int cl = wc * 32 + nr * 16 + l15;
        sred[0][cl][wr] = s;
        sred[1][cl][wr] = q;
      }
    }
    __syncthreads();
    if (tid < 128) {
      const int which = tid >> 6;
      const int cl = tid & 63;
      const float tot = sred[which][cl][0] + sred[which][cl][1];
      float* dstp = which ? colsumsq : colsum;
      atomicAdd(&dstp[col0 + cl], tot);
    }
  }
}

// ---------------- degree histogram ----------------
__global__ void hist_kernel(const int* __restrict__ dst, int* __restrict__ hist, int E) {
  const int e = blockIdx.x * 256 + threadIdx.x;
  if (e < E) atomicAdd(&hist[dst[e]], 1);
}

// ---------------- two-level exclusive scan (scan1 also emits nisq) ----------------
__global__ __launch_bounds__(1024) void scan1_kernel(
    const int* __restrict__ hist, int* __restrict__ off, int* __restrict__ partial,
    float* __restrict__ nisq, int n) {
  __shared__ int tmp[1024];
  const int tid = threadIdx.x;
  const int i = blockIdx.x * 1024 + tid;
  const int v = (i < n) ? hist[i] : 0;
  tmp[tid] = v;
  __syncthreads();
  int x = v;
  for (int o = 1; o < 1024; o <<= 1) {
    const int y = (tid >= o) ? tmp[tid - o] : 0;
    __syncthreads();
    x += y;
    tmp[tid] = x;
    __syncthreads();
  }
  if (i < n) {
    off[i] = x - v;
    nisq[i] = rsqrtf((float)v + 1.0f);
  }
  if (tid == 1023) partial[blockIdx.x] = x;
}

__global__ __launch_bounds__(64) void scan2_kernel(
    const int* __restrict__ partial, int* __restrict__ partialoff,
    int* __restrict__ offN, int nb) {
  const int tid = threadIdx.x;
  const int v = (tid < nb) ? partial[tid] : 0;
  int x = v;
  for (int o = 1; o < 64; o <<= 1) {
    const int y = __shfl_up(x, o, 64);
    if (tid >= o) x += y;
  }
  if (tid < nb) partialoff[tid] = x - v;
  if (tid == 63) *offN = x;
}

__global__ void scan3_kernel(int* __restrict__ off, int* __restrict__ cursor,
                             const int* __restrict__ partialoff, int n) {
  const int i = blockIdx.x * 256 + threadIdx.x;
  if (i < n) {
    const int o = off[i] + partialoff[i >> 10];
    off[i] = o;
    cursor[i] = o;
  }
}

// ---------------- scatter edges into dst-sorted order ----------------
__global__ void scatter_kernel(const int* __restrict__ src, const int* __restrict__ dst,
                               int* __restrict__ cursor, int* __restrict__ esorted, int E) {
  const int e = blockIdx.x * 256 + threadIdx.x;
  if (e < E) {
    const int p = atomicAdd(&cursor[dst[e]], 1);
    esorted[p] = src[e];
  }
}

// ---------------- scale+cast: xs = bf16(x * nisq[row]), DI=128 ----------------
__global__ void scale_cast_kernel(const float* __restrict__ x,
                                  const float* __restrict__ nisq,
                                  unsigned short* __restrict__ xs) {
  const int idx = blockIdx.x * 256 + threadIdx.x;
  if (idx >= N_NODES * 32) return;
  const int row = idx >> 5;
  const int c = (idx & 31) * 4;
  const float s = nisq[row];
  const float4 v = *reinterpret_cast<const float4*>(&x[(size_t)row * 128 + c]);
  ushort4 o;
  o.x = f2bf(v.x * s); o.y = f2bf(v.y * s);
  o.z = f2bf(v.z * s); o.w = f2bf(v.w * s);
  *reinterpret_cast<ushort4*>(&xs[(size_t)row * 128 + c]) = o;
}

// ---------------- pure gather aggregation (half-wave, 16B/lane); zeroes pad rows ----------------
template <int DO, bool ADD_BIAS, bool HAS_RES, bool OUT_BF16>
__global__ __launch_bounds__(256) void aggregate4_kernel(
    const unsigned short* __restrict__ Y, const int* __restrict__ segoff,
    const int* __restrict__ esorted, const float* __restrict__ nisq,
    const float* __restrict__ bias, const float* __restrict__ resid,
    void* __restrict__ Tv) {
  constexpr int V2 = DO / 32;  // bf16 elems per lane per row (128: 4, 256: 8)
  const int wave = threadIdx.x >> 6;
  const int lane = threadIdx.x & 63;
  const int half = lane >> 5;
  const int l31 = lane & 31;
  const int n = blockIdx.x * 4 + wave;
  const int colbase = l31 * V2;
  if (n >= N_NODES) {  // pad row: write zeros so GEMM can load unguarded
    if (half == 0) {
      if constexpr (OUT_BF16) {
        unsigned short* tr = (unsigned short*)Tv + (size_t)n * DO + colbase;
        if constexpr (V2 == 8) *reinterpret_cast<uint4*>(tr) = (uint4){0, 0, 0, 0};
        else *reinterpret_cast<uint2*>(tr) = (uint2){0, 0};
      } else {
        float* tr = (float*)Tv + (size_t)n * DO + colbase;
        if constexpr (V2 == 8) {
          *reinterpret_cast<float4*>(tr) = (float4){0.f, 0.f, 0.f, 0.f};
          *reinterpret_cast<float4*>(tr + 4) = (float4){0.f, 0.f, 0.f, 0.f};
        } else {
          *reinterpret_cast<float4*>(tr) = (float4){0.f, 0.f, 0.f, 0.f};
        }
      }
    }
    return;
  }
  const unsigned short* Yc = Y + colbase;
  float a0[V2], a1[V2];
#pragma unroll
  for (int i = 0; i < V2; ++i) { a0[i] = 0.f; a1[i] = 0.f; }
  const int s = segoff[n];
  const int e = segoff[n + 1];

  if constexpr (V2 == 8) {
    auto acc8 = [&](float* a, const uint4 v) {
      a[0] += bflo(v.x); a[1] += bfhi(v.x);
      a[2] += bflo(v.y); a[3] += bfhi(v.y);
      a[4] += bflo(v.z); a[5] += bfhi(v.z);
      a[6] += bflo(v.w); a[7] += bfhi(v.w);
    };
    int j = s + half;
    for (; j + 2 < e; j += 4) {
      const int i0 = esorted[j];
      const int i1 = esorted[j + 2];
      const uint4 v0 = *reinterpret_cast<const uint4*>(Yc + (size_t)i0 * DO);
      const uint4 v1 = *reinterpret_cast<const uint4*>(Yc + (size_t)i1 * DO);
      acc8(a0, v0); acc8(a1, v1);
    }
    if (j < e) acc8(a0, *reinterpret_cast<const uint4*>(Yc + (size_t)esorted[j] * DO));
    if (half == 0) acc8(a1, *reinterpret_cast<const uint4*>(Yc + (size_t)n * DO));
  } else {
    auto acc4 = [&](float* a, const uint2 v) {
      a[0] += bflo(v.x); a[1] += bfhi(v.x);
      a[2] += bflo(v.y); a[3] += bfhi(v.y);
    };
    int j = s + half;
    for (; j + 2 < e; j += 4) {
      const int i0 = esorted[j];
      const int i1 = esorted[j + 2];
      const uint2 v0 = *reinterpret_cast<const uint2*>(Yc + (size_t)i0 * DO);
      const uint2 v1 = *reinterpret_cast<const uint2*>(Yc + (size_t)i1 * DO);
      acc4(a0, v0); acc4(a1, v1);
    }
    if (j < e) acc4(a0, *reinterpret_cast<const uint2*>(Yc + (size_t)esorted[j] * DO));
    if (half == 0) acc4(a1, *reinterpret_cast<const uint2*>(Yc + (size_t)n * DO));
  }

  const float sc = nisq[n];
  float vals[V2];
#pragma unroll
  for (int i = 0; i < V2; ++i) {
    float t = a0[i] + a1[i];
    t += __shfl_xor(t, 32, 64);
    t *= sc;
    if (half == 0) {
      if (ADD_BIAS) t += bias[colbase + i];
      if (HAS_RES) t += resid[(size_t)n * DO + colbase + i];
    }
    vals[i] = t;
  }
  if (half == 0) {
    if constexpr (OUT_BF16) {
      unsigned short* tr = (unsigned short*)Tv + (size_t)n * DO + colbase;
      if constexpr (V2 == 8) {
        uint4 o;
        o.x = packbf(vals[0], vals[1]); o.y = packbf(vals[2], vals[3]);
        o.z = packbf(vals[4], vals[5]); o.w = packbf(vals[6], vals[7]);
        *reinterpret_cast<uint4*>(tr) = o;
      } else {
        uint2 o;
        o.x = packbf(vals[0], vals[1]); o.y = packbf(vals[2], vals[3]);
        *reinterpret_cast<uint2*>(tr) = o;
      }
    } else {
      float* tr = (float*)Tv + (size_t)n * DO + colbase;
      if constexpr (V2 == 8) {
        float4 o0 = {vals[0], vals[1], vals[2], vals[3]};
        float4 o1 = {vals[4], vals[5], vals[6], vals[7]};
        *reinterpret_cast<float4*>(tr) = o0;
        *reinterpret_cast<float4*>(tr + 4) = o1;
      } else {
        float4 o = {vals[0], vals[1], vals[2], vals[3]};
        *reinterpret_cast<float4*>(tr) = o;
      }
    }
  }
}

// ---------------- column sums for BN stats (f32 input, L4 only) ----------------
__global__ void stats_kernel(const float* __restrict__ T, float* __restrict__ colsum,
                             float* __restrict__ colsumsq, int n, int rowsPerBlock) {
  const int c = threadIdx.x;
  const int DO = blockDim.x;
  const int r0 = blockIdx.x * rowsPerBlock;
  int r1 = r0 + rowsPerBlock;
  if (r1 > n) r1 = n;
  float s = 0.f, q = 0.f;
  for (int r = r0; r < r1; ++r) {
    const float v = T[(size_t)r * DO + c];
    s += v;
    q += v * v;
  }
  atomicAdd(&colsum[c], s);
  atomicAdd(&colsumsq[c], q);
}

// ---------------- BN apply + LeakyReLU + nisq row-scale, bf16 -> bf16 (DO=256); zero pads ----
__global__ void bn_lrelu_nisq_kernel(const unsigned short* __restrict__ Tb,
                                     const float* __restrict__ colsum,
                                     const float* __restrict__ colsumsq,
                                     const float* __restrict__ g, const float* __restrict__ be,
                                     const float* __restrict__ nisq,
                                     unsigned short* __restrict__ outb,
                                     size_t total8, float invN) {
  const size_t idx = (size_t)blockIdx.x * 256 + threadIdx.x;
  if (idx >= total8) return;
  const int row = (int)(idx >> 5);
  if (row >= N_NODES) {  // pad row: table must stay zero for next GEMM
    *reinterpret_cast<uint4*>(&outb[idx * 8]) = (uint4){0, 0, 0, 0};
    return;
  }
  const unsigned c = ((unsigned)idx & 31u) * 8;
  const float sc = nisq[row];
  uint4 v = *reinterpret_cast<const uint4*>(&Tb[idx * 8]);
  float z[8] = {bflo(v.x), bfhi(v.x), bflo(v.y), bfhi(v.y),
                bflo(v.z), bfhi(v.z), bflo(v.w), bfhi(v.w)};
  const float4 cs0 = *reinterpret_cast<const float4*>(&colsum[c]);
  const float4 cs1 = *reinterpret_cast<const float4*>(&colsum[c + 4]);
  const float4 cq0 = *reinterpret_cast<const float4*>(&colsumsq[c]);
  const float4 cq1 = *reinterpret_cast<const float4*>(&colsumsq[c + 4]);
  const float4 gv0 = *reinterpret_cast<const float4*>(&g[c]);
  const float4 gv1 = *reinterpret_cast<const float4*>(&g[c + 4]);
  const float4 bv0 = *reinterpret_cast<const float4*>(&be[c]);
  const float4 bv1 = *reinterpret_cast<const float4*>(&be[c + 4]);
  const float css[8] = {cs0.x, cs0.y, cs0.z, cs0.w, cs1.x, cs1.y, cs1.z, cs1.w};
  const float cqq[8] = {cq0.x, cq0.y, cq0.z, cq0.w, cq1.x, cq1.y, cq1.z, cq1.w};
  const float ggg[8] = {gv0.x, gv0.y, gv0.z, gv0.w, gv1.x, gv1.y, gv1.z, gv1.w};
  const float bbb[8] = {bv0.x, bv0.y, bv0.z, bv0.w, bv1.x, bv1.y, bv1.z, bv1.w};
#pragma unroll
  for (int k = 0; k < 8; ++k) {
    const float m = css[k] * invN;
    const float rs = rsqrtf(cqq[k] * invN - m * m + EPS_C);
    float zz = (z[k] - m) * rs * ggg[k] + bbb[k];
    zz = (zz >= 0.f) ? zz : SLOPE_C * zz;
    z[k] = zz * sc;
  }
  v.x = packbf(z[0], z[1]); v.y = packbf(z[2], z[3]);
  v.z = packbf(z[4], z[5]); v.w = packbf(z[6], z[7]);
  *reinterpret_cast<uint4*>(&outb[idx * 8]) = v;
}

// ---------------- final: BN apply + LayerNorm fused (DO=128) ----------------
__global__ __launch_bounds__(256) void bn_ln_kernel(
    const float* __restrict__ T, const float* __restrict__ colsum,
    const float* __restrict__ colsumsq, const float* __restrict__ g,
    const float* __restrict__ be, const float* __restrict__ lng,
    const float* __restrict__ lnb, float* __restrict__ out, float invN) {
  const int wave = threadIdx.x >> 6;
  const int lane = threadIdx.x & 63;
  const int n = blockIdx.x * 4 + wave;
  if (n >= N_NODES) return;
  const int c = lane * 2;
  const float2 t = *reinterpret_cast<const float2*>(&T[(size_t)n * 128 + c]);
  float z[2];
#pragma unroll
  for (int k = 0; k < 2; ++k) {
    const float m = colsum[c + k] * invN;
    const float v = colsumsq[c + k] * invN - m * m;
    const float tv = (k == 0) ? t.x : t.y;
    z[k] = (tv - m) * rsqrtf(v + EPS_C) * g[c + k] + be[c + k];
  }
  float s = z[0] + z[1];
  float q = z[0] * z[0] + z[1] * z[1];
  for (int o = 32; o > 0; o >>= 1) {
    s += __shfl_xor(s, o, 64);
    q += __shfl_xor(q, o, 64);
  }
  const float mean = s * (1.f / 128.f);
  const float var = q * (1.f / 128.f) - mean * mean;
  const float rs = rsqrtf(var + EPS_C);
  float2 o2;
  o2.x = (z[0] - mean) * rs * lng[c] + lnb[c];
  o2.y = (z[1] - mean) * rs * lng[c + 1] + lnb[c + 1];
  *reinterpret_cast<float2*>(&out[(size_t)n * 128 + c]) = o2;
}

extern "C" void kernel_launch(void* const* d_in, const int* in_sizes, int n_in,
                              void* d_out, int out_size, void* d_ws, size_t ws_size,
                              hipStream_t stream) {
  const float* x = (const float*)d_in[0];
  const int* ei = (const int*)d_in[1];
  const int* srcp = ei;
  const int* dstp = ei + N_EDGES;
  const float* W1 = (const float*)d_in[2];
  const float* b1 = (const float*)d_in[3];
  const float* g1 = (const float*)d_in[4];
  const float* be1 = (const float*)d_in[5];
  const float* W2 = (const float*)d_in[6];
  const float* b2 = (const float*)d_in[7];
  const float* g2 = (const float*)d_in[8];
  const float* be2 = (const float*)d_in[9];
  const float* W3 = (const float*)d_in[10];
  const float* b3 = (const float*)d_in[11];
  const float* g3 = (const float*)d_in[12];
  const float* be3 = (const float*)d_in[13];
  const float* W4 = (const float*)d_in[14];
  const float* b4 = (const float*)d_in[15];
  const float* g4 = (const float*)d_in[16];
  const float* be4 = (const float*)d_in[17];
  const float* lng = (const float*)d_in[18];
  const float* lnb = (const float*)d_in[19];
  float* out = (float*)d_out;

  char* ws = (char*)d_ws;
  size_t off_b = 0;
  auto alloc = [&](size_t bytes) -> void* {
    void* p = (void*)(ws + off_b);
    off_b += (bytes + 255) & ~(size_t)255;
    return p;
  };
  // ---- zero-region (one memset): hist + per-layer stats buffers ----
  int* hist = (int*)alloc((size_t)N_NODES * 4);
  float* cs1 = (float*)alloc(256 * 4);
  float* cq1 = (float*)alloc(256 * 4);
  float* cs2 = (float*)alloc(256 * 4);
  float* cq2 = (float*)alloc(256 * 4);
  float* cs3 = (float*)alloc(256 * 4);
  float* cq3 = (float*)alloc(256 * 4);
  float* cs4 = (float*)alloc(256 * 4);
  float* cq4 = (float*)alloc(256 * 4);
  const size_t zero_bytes = off_b;
  // ---- rest ----
  int* segoff = (int*)alloc((size_t)(N_NODES + 1) * 4);
  int* cursor = (int*)alloc((size_t)N_NODES * 4);
  float* nisq = (float*)alloc((size_t)N_NODES * 4);
  int* esorted = (int*)alloc((size_t)N_EDGES * 4);
  int* partial = (int*)alloc(64 * 4);
  int* partialoff = (int*)alloc(64 * 4);
  unsigned short* Wt1 = (unsigned short*)alloc((size_t)256 * 128 * 2);
  unsigned short* Wt2 = (unsigned short*)alloc((size_t)256 * 256 * 2);
  unsigned short* Wt3 = (unsigned short*)alloc((size_t)256 * 256 * 2);
  unsigned short* Wt4 = (unsigned short*)alloc((size_t)128 * 256 * 2);
  unsigned short* tblA = (unsigned short*)alloc((size_t)NPAD * 256 * 2);
  unsigned short* tblB = (unsigned short*)alloc((size_t)NPAD * 256 * 2);
  unsigned short* S = (unsigned short*)alloc((size_t)NPAD * 256 * 2);
  unsigned short* Tb = (unsigned short*)alloc((size_t)NPAD * 256 * 2);
  float* Tf = (float*)alloc((size_t)NPAD * 128 * 4);

  const float invN = 1.0f / (float)N_NODES;
  const int egrid = (N_EDGES + 255) / 256;
  const int ngrid = (N_NODES + 255) / 256;
  const int aggrid = NPAD / 4;             // covers pad rows (zero-writers)
  const int statgrid = (N_NODES + 127) / 128;
  const int nb = (N_NODES + 1023) / 1024;
  const dim3 mgrid256(NPAD / 128, 4);
  const dim3 mgrid128(NPAD / 128, 2);
  const unsigned bngrid = (unsigned)(((size_t)NPAD * 32 + 255) / 256);

  // ---- zero hist + all stats buffers in ONE memset ----
  hipMemsetAsync(hist, 0, zero_bytes, stream);

  // ---- degrees + nisq + dst-sorted edge list (counting sort) ----
  hist_kernel<<<egrid, 256, 0, stream>>>(dstp, hist, N_EDGES);
  scan1_kernel<<<nb, 1024, 0, stream>>>(hist, segoff, partial, nisq, N_NODES);
  scan2_kernel<<<1, 64, 0, stream>>>(partial, partialoff, &segoff[N_NODES], nb);
  scan3_kernel<<<ngrid, 256, 0, stream>>>(segoff, cursor, partialoff, N_NODES);
  scatter_kernel<<<egrid, 256, 0, stream>>>(srcp, dstp, cursor, esorted, N_EDGES);

  // ---- weights transpose+cast (one dispatch) ----
  wcast_all_kernel<<<dim3(256, 4), 256, 0, stream>>>(W1, W2, W3, W4, Wt1, Wt2, Wt3, Wt4);

  // ---- Layer 1: tblA = x*nisq; S = A_hat-gather; Tb = S W1 + b1 (+stats); bn*nisq -> tblB
  scale_cast_kernel<<<(N_NODES * 32 + 255) / 256, 256, 0, stream>>>(x, nisq, tblA);
  aggregate4_kernel<128, false, false, true><<<aggrid, 256, 0, stream>>>(
      tblA, segoff, esorted, nisq, nullptr, nullptr, S);
  gemm2_kernel<1, 128><<<mgrid256, 256, 0, stream>>>(S, Wt1, b1, Tb, cs1, cq1, 256);
  bn_lrelu_nisq_kernel<<<bngrid, 256, 0, stream>>>(Tb, cs1, cq1, g1, be1, nisq,
                                                   tblB, (size_t)NPAD * 32, invN);

  // ---- Layer 2 ----
  aggregate4_kernel<256, false, false, true><<<aggrid, 256, 0, stream>>>(
      tblB, segoff, esorted, nisq, nullptr, nullptr, S);
  gemm2_kernel<1, 256><<<mgrid256, 256, 0, stream>>>(S, Wt2, b2, Tb, cs2, cq2, 256);
  bn_lrelu_nisq_kernel<<<bngrid, 256, 0, stream>>>(Tb, cs2, cq2, g2, be2, nisq,
                                                   tblA, (size_t)NPAD * 32, invN);

  // ---- Layer 3 ----
  aggregate4_kernel<256, false, false, true><<<aggrid, 256, 0, stream>>>(
      tblA, segoff, esorted, nisq, nullptr, nullptr, S);
  gemm2_kernel<1, 256><<<mgrid256, 256, 0, stream>>>(S, Wt3, b3, Tb, cs3, cq3, 256);
  bn_lrelu_nisq_kernel<<<bngrid, 256, 0, stream>>>(Tb, cs3, cq3, g3, be3, nisq,
                                                   tblB, (size_t)NPAD * 32, invN);

  // ---- Layer 4: S = tblB·W4 (nisq pre-folded); agg(+b4+resid) -> f32; stats; BN+LN ----
  gemm2_kernel<0, 256><<<mgrid128, 256, 0, stream>>>(tblB, Wt4, nullptr, S, nullptr, nullptr, 128);
  aggregate4_kernel<128, true, true, false><<<aggrid, 256, 0, stream>>>(
      S, segoff, esorted, nisq, b4, x, Tf);
  stats_kernel<<<statgrid, 128, 0, stream>>>(Tf, cs4, cq4, N_NODES, 128);
  bn_ln_kernel<<<(N_NODES + 3) / 4, 256, 0, stream>>>(Tf, cs4, cq4, g4, be4, lng, lnb, out, invN);
}